// Round 4
// baseline (3478.009 us; speedup 1.0000x reference)
//
#include <hip/hip_runtime.h>
#include <cmath>
#include <cstdint>
#include <cstddef>
#include <climits>

#define N_SRC 65536
#define N_TGT 1024
#define DIM   256
#define TAU_INV (1.0f/0.07f)
#define LOSS_EPS 1e-6f
#define TOPSEL 512
#define NBI (N_SRC/128)     // 512 row-blocks (M-tiles of 128)
#define NBJ (N_TGT/64)      // 16 col-blocks (N-tiles of 64)

typedef __bf16 bf16x8 __attribute__((ext_vector_type(8)));
typedef float  f32x4  __attribute__((ext_vector_type(4)));

// ---------------- bf16 split helpers ------------------------------------------------
__device__ __forceinline__ unsigned short f2bf(float x) {
  unsigned u = __float_as_uint(x);
  unsigned r = (u + 0x7fffu + ((u >> 16) & 1u)) >> 16;
  return (unsigned short)r;
}
__device__ __forceinline__ float bf2f(unsigned short h) {
  return __uint_as_float(((unsigned)h) << 16);
}

// ---------------- top-5 insertion helpers -------------------------------------------
__device__ __forceinline__ void insert5_vi(float v[5], int id[5], float nv, int ni) {
  bool beats_last = (nv > v[4]) || (nv == v[4] && ni < id[4]);
  if (!beats_last) return;
  #pragma unroll
  for (int p = 4; p > 0; --p) {
    bool up = (nv > v[p-1]) || (nv == v[p-1] && ni < id[p-1]);
    if (up) { v[p] = v[p-1]; id[p] = id[p-1]; }
    else    { v[p] = nv; id[p] = ni; return; }
  }
  v[0] = nv; id[0] = ni;
}
__device__ __forceinline__ void insert5_v(float v[5], float nv) {
  if (!(nv > v[4])) return;
  #pragma unroll
  for (int p = 4; p > 0; --p) {
    if (nv > v[p-1]) v[p] = v[p-1];
    else { v[p] = nv; return; }
  }
  v[0] = nv;
}
__device__ __forceinline__ void wave_merge5_vi(float v[5], int id[5]) {
  #pragma unroll
  for (int off = 1; off < 64; off <<= 1) {
    float pv[5]; int pi[5];
    #pragma unroll
    for (int u = 0; u < 5; ++u) {
      pv[u] = __shfl_xor(v[u], off, 64);
      pi[u] = __shfl_xor(id[u], off, 64);
    }
    #pragma unroll
    for (int u = 0; u < 5; ++u) insert5_vi(v, id, pv[u], pi[u]);
  }
}
__device__ __forceinline__ void wave_merge5_v(float v[5]) {
  #pragma unroll
  for (int off = 1; off < 64; off <<= 1) {
    float pv[5];
    #pragma unroll
    for (int u = 0; u < 5; ++u) pv[u] = __shfl_xor(v[u], off, 64);
    #pragma unroll
    for (int u = 0; u < 5; ++u) insert5_v(v, pv[u]);
  }
}

// ---------------- K1: row-normalize + split fp32 -> (hi, lo) bf16 -------------------
__global__ __launch_bounds__(256) void k_norm_split(const float* __restrict__ X,
                                                    unsigned short* __restrict__ hi,
                                                    unsigned short* __restrict__ lo) {
  int wave = threadIdx.x >> 6, lane = threadIdx.x & 63;
  int row  = blockIdx.x * 4 + wave;
  float4 v = reinterpret_cast<const float4*>(X + (size_t)row * DIM)[lane];
  float ss = v.x*v.x + v.y*v.y + v.z*v.z + v.w*v.w;
  #pragma unroll
  for (int o = 32; o > 0; o >>= 1) ss += __shfl_xor(ss, o, 64);
  float r = 1.0f / sqrtf(ss);
  v.x *= r; v.y *= r; v.z *= r; v.w *= r;
  ushort4 h, l;
  h.x = f2bf(v.x); l.x = f2bf(v.x - bf2f(h.x));
  h.y = f2bf(v.y); l.y = f2bf(v.y - bf2f(h.y));
  h.z = f2bf(v.z); l.z = f2bf(v.z - bf2f(h.z));
  h.w = f2bf(v.w); l.w = f2bf(v.w - bf2f(h.w));
  reinterpret_cast<ushort4*>(hi + (size_t)row * DIM)[lane] = h;
  reinterpret_cast<ushort4*>(lo + (size_t)row * DIM)[lane] = l;
}

// ---------------- K2: barrier-free "flatmm" fused GEMM ------------------------------
// Tile 128(M) x 64(N), K'=768 over segments {(Ahi,Bhi),(Alo,Bhi),(Ahi,Blo)}.
// B panel (64 cols x 512 k' = hi||lo) preloaded ONCE into 64KB LDS, XOR-swizzled
// (byte ^= (col&7)<<4) to break the 1024B-stride 16-way bank conflict; reg-staged
// write so swizzle is on both sides (write & read). K-loop: A frags global->reg
// (16 rows x 64B contiguous per instr), B frags from LDS, 8 indep MFMA/step.
// ZERO barriers in the K-loop -> per-wave vmcnt pipelining, no collective drain.
// 4 waves in 2x2: wm=row-half(64), wn=col-half(32); per wave 4 rf x 2 cf frags.
// PHASE 1 epilogue: per-col top-5 (val, global idx).
// PHASE 2 epilogue: per-col {sum exp, sum exp matched, top5 matched, top5 unmatched}.
template<int PHASE>
__global__ __launch_bounds__(256) void k_gemm_fused(
    const unsigned short* __restrict__ Ahi, const unsigned short* __restrict__ Alo,
    const unsigned short* __restrict__ Bhi, const unsigned short* __restrict__ Blo,
    const int* __restrict__ labels, const int* __restrict__ assigned,
    float* __restrict__ p1v, int* __restrict__ p1i, float* __restrict__ p2p)
{
  __shared__ unsigned short Bs[64 * 512];   // 64KB; reused as epilogue scratch
  __shared__ int lab_s[128];
  __shared__ int asg_s[64];

  const int tid  = threadIdx.x;
  const int lane = tid & 63;
  const int w    = tid >> 6;
  const int wm   = w & 1;          // row half (64 rows)
  const int wn   = w >> 1;         // col half (32 cols)

  // bijective XCD-locality remap: 16 consecutive-on-XCD blocks share one A panel
  const int d  = blockIdx.x;               // grid = NBI*NBJ = 8192
  const int c  = d & 7;
  const int kk = d >> 3;
  const int bj = kk & 15;
  const int bi = ((kk >> 4) << 3) | c;
  const int i0 = bi * 128;
  const int j0 = bj * 64;

  // ---- B panel preload (reg-staged, swizzled dest) --------------------------------
  {
    const unsigned short* BH = Bhi + (size_t)j0 * DIM;
    const unsigned short* BL = Blo + (size_t)j0 * DIM;
    #pragma unroll
    for (int i = 0; i < 16; ++i) {
      int e16 = i * 256 + tid;             // 16B-chunk index 0..4095
      int col = e16 >> 6;                  // 0..63
      int c16 = e16 & 63;                  // 64 chunks per 1KB row (hi:0-31, lo:32-63)
      const unsigned short* src = (c16 < 32) ? (BH + col * DIM + c16 * 8)
                                             : (BL + col * DIM + (c16 - 32) * 8);
      bf16x8 v = *(const bf16x8*)src;
      int dst = col * 1024 + ((c16 * 16) ^ ((col & 7) << 4));
      *(bf16x8*)((char*)Bs + dst) = v;
    }
  }
  if constexpr (PHASE == 2) {
    if (tid < 128) lab_s[tid] = labels[i0 + tid];
    if (tid < 64)  asg_s[tid] = assigned[j0 + tid];
  }
  __syncthreads();                          // the ONLY barrier before the epilogue

  f32x4 acc[4][2];
  #pragma unroll
  for (int a = 0; a < 4; ++a)
    #pragma unroll
    for (int b = 0; b < 2; ++b) acc[a][b] = f32x4{0.f, 0.f, 0.f, 0.f};

  const int fr = lane & 15;
  const int fq = lane >> 4;                 // 0..3
  const int fk = fq << 3;                   // k offset 0,8,16,24

  // hoisted A row pointers (per rf, hi & lo)
  const unsigned short* aH[4]; const unsigned short* aL[4];
  #pragma unroll
  for (int rf = 0; rf < 4; ++rf) {
    size_t ro = (size_t)(i0 + (wm << 6) + (rf << 4) + fr) * DIM + fk;
    aH[rf] = Ahi + ro; aL[rf] = Alo + ro;
  }
  // hoisted B column bases + swizzle
  int colb[2], sw[2];
  #pragma unroll
  for (int cf = 0; cf < 2; ++cf) {
    int col = (wn << 5) + (cf << 4) + fr;
    colb[cf] = col << 10;
    sw[cf]   = (col & 7) << 4;
  }
  const int fk2 = fk << 1;                  // byte offset of fk within row

  #pragma unroll
  for (int t = 0; t < 24; ++t) {
    const int seg = t >> 3;                 // 0:hh 1:lh 2:hl
    const int kc  = (t & 7) << 5;           // k within segment
    bf16x8 a[4], b[2];
    #pragma unroll
    for (int rf = 0; rf < 4; ++rf)
      a[rf] = *(const bf16x8*)((seg == 1 ? aL[rf] : aH[rf]) + kc);
    #pragma unroll
    for (int cf = 0; cf < 2; ++cf) {
      int off = ((seg == 2 ? 512 : 0) + (kc << 1) + fk2) ^ sw[cf];
      b[cf] = *(const bf16x8*)((char*)Bs + colb[cf] + off);
    }
    #pragma unroll
    for (int rf = 0; rf < 4; ++rf)
      #pragma unroll
      for (int cf = 0; cf < 2; ++cf)
        acc[rf][cf] = __builtin_amdgcn_mfma_f32_16x16x32_bf16(a[rf], b[cf], acc[rf][cf], 0, 0, 0);
  }

  // acc map: col n = wn*32+cf*16+(lane&15); row m = wm*64+rf*16+fq*4+reg
  __syncthreads();                          // all waves done reading Bs -> scratch

  if constexpr (PHASE == 1) {
    float* ep_v = reinterpret_cast<float*>(Bs);          // [2][64][5]
    int*   ep_i = reinterpret_cast<int*>(Bs) + 640;      // [2][64][5]
    #pragma unroll
    for (int cf = 0; cf < 2; ++cf) {
      float tv[5]; int ti[5];
      #pragma unroll
      for (int u = 0; u < 5; ++u) { tv[u] = -INFINITY; ti[u] = INT_MAX; }
      #pragma unroll
      for (int rf = 0; rf < 4; ++rf) {
        const int mb = i0 + (wm << 6) + (rf << 4) + (fq << 2);
        #pragma unroll
        for (int r = 0; r < 4; ++r) insert5_vi(tv, ti, acc[rf][cf][r], mb + r);
      }
      #pragma unroll
      for (int off = 16; off < 64; off <<= 1) {
        float pv[5]; int pi[5];
        #pragma unroll
        for (int u = 0; u < 5; ++u) { pv[u] = __shfl_xor(tv[u], off, 64); pi[u] = __shfl_xor(ti[u], off, 64); }
        #pragma unroll
        for (int u = 0; u < 5; ++u) insert5_vi(tv, ti, pv[u], pi[u]);
      }
      if (lane < 16) {
        const int col = (wn << 5) + (cf << 4) + lane;
        #pragma unroll
        for (int u = 0; u < 5; ++u) { ep_v[(wm*64 + col)*5 + u] = tv[u]; ep_i[(wm*64 + col)*5 + u] = ti[u]; }
      }
    }
    __syncthreads();
    if (tid < 64) {
      float v[5]; int id[5];
      #pragma unroll
      for (int u = 0; u < 5; ++u) { v[u] = -INFINITY; id[u] = INT_MAX; }
      #pragma unroll
      for (int h = 0; h < 2; ++h)
        #pragma unroll
        for (int u = 0; u < 5; ++u)
          insert5_vi(v, id, ep_v[(h*64 + tid)*5 + u], ep_i[(h*64 + tid)*5 + u]);
      const size_t o = ((size_t)(j0 + tid) * NBI + bi) * 5;
      #pragma unroll
      for (int u = 0; u < 5; ++u) { p1v[o+u] = v[u]; p1i[o+u] = id[u]; }
    }
  } else {
    float* ep = reinterpret_cast<float*>(Bs);            // [2][64][12]
    #pragma unroll
    for (int cf = 0; cf < 2; ++cf) {
      const int col = (wn << 5) + (cf << 4) + fr;
      const int asg = asg_s[col];
      float se = 0.f, sem = 0.f;
      float mt[5], ut[5];
      #pragma unroll
      for (int u = 0; u < 5; ++u) { mt[u] = -INFINITY; ut[u] = -INFINITY; }
      #pragma unroll
      for (int rf = 0; rf < 4; ++rf) {
        const int mb = (wm << 6) + (rf << 4) + (fq << 2);
        #pragma unroll
        for (int r = 0; r < 4; ++r) {
          const float val = acc[rf][cf][r];
          const float e = __expf(val * TAU_INV);
          se += e;
          if (lab_s[mb + r] == asg) { sem += e; insert5_v(mt, val); }
          else insert5_v(ut, val);
        }
      }
      #pragma unroll
      for (int off = 16; off < 64; off <<= 1) {
        se  += __shfl_xor(se,  off, 64);
        sem += __shfl_xor(sem, off, 64);
        float pm[5], pu[5];
        #pragma unroll
        for (int u = 0; u < 5; ++u) { pm[u] = __shfl_xor(mt[u], off, 64); pu[u] = __shfl_xor(ut[u], off, 64); }
        #pragma unroll
        for (int u = 0; u < 5; ++u) { insert5_v(mt, pm[u]); insert5_v(ut, pu[u]); }
      }
      if (lane < 16) {
        float* dst = ep + (wm*64 + col) * 12;
        dst[0] = se; dst[1] = sem;
        #pragma unroll
        for (int u = 0; u < 5; ++u) { dst[2+u] = mt[u]; dst[7+u] = ut[u]; }
      }
    }
    __syncthreads();
    if (tid < 64) {
      const float* a = ep + (size_t)tid * 12;
      const float* b = ep + (size_t)(64 + tid) * 12;
      float se = a[0] + b[0], sem = a[1] + b[1];
      float mt[5], ut[5];
      #pragma unroll
      for (int u = 0; u < 5; ++u) { mt[u] = -INFINITY; ut[u] = -INFINITY; }
      #pragma unroll
      for (int u = 0; u < 5; ++u) {
        insert5_v(mt, a[2+u]); insert5_v(mt, b[2+u]);
        insert5_v(ut, a[7+u]); insert5_v(ut, b[7+u]);
      }
      const size_t o = ((size_t)(j0 + tid) * NBI + bi) * 12;
      p2p[o+0] = se; p2p[o+1] = sem;
      #pragma unroll
      for (int u = 0; u < 5; ++u) { p2p[o+2+u] = mt[u]; p2p[o+7+u] = ut[u]; }
    }
  }
}

// ---------------- K3: merge row-block top-5s -> assigned label per column -----------
__global__ __launch_bounds__(256) void k_assign2(const float* __restrict__ p1v,
                                                 const int* __restrict__ p1i,
                                                 const int* __restrict__ labels,
                                                 int* __restrict__ assigned) {
  const int w = threadIdx.x >> 6, lane = threadIdx.x & 63;
  const int j = blockIdx.x * 4 + w;
  const float* pv = p1v + (size_t)j * NBI * 5;
  const int*   pi = p1i + (size_t)j * NBI * 5;
  float v[5]; int id[5];
  #pragma unroll
  for (int u = 0; u < 5; ++u) { v[u] = -INFINITY; id[u] = INT_MAX; }
  for (int b = lane; b < NBI; b += 64) {
    #pragma unroll
    for (int u = 0; u < 5; ++u) insert5_vi(v, id, pv[b*5 + u], pi[b*5 + u]);
  }
  wave_merge5_vi(v, id);
  if (lane == 0) {
    int lab[5];
    #pragma unroll
    for (int a = 0; a < 5; ++a) lab[a] = labels[id[a]];
    int bestSc = INT_MIN, bestA = 0;
    #pragma unroll
    for (int a = 0; a < 5; ++a) {
      int cnt = 0;
      #pragma unroll
      for (int b = 0; b < 5; ++b) cnt += (lab[b] == lab[a]) ? 1 : 0;
      int sc = cnt * 1000000 - lab[a];
      if (sc > bestSc) { bestSc = sc; bestA = a; }
    }
    assigned[j] = lab[bestA];
  }
}

// ---------------- K4: merge row-block stats -> scores, contrast ---------------------
__global__ __launch_bounds__(256) void k_score2(const float* __restrict__ p2p,
                                                float* __restrict__ scores,
                                                float* __restrict__ contrast) {
  const int w = threadIdx.x >> 6, lane = threadIdx.x & 63;
  const int j = blockIdx.x * 4 + w;
  const float* p = p2p + (size_t)j * NBI * 12;
  float se = 0.f, sem = 0.f;
  float mt[5], ut[5];
  #pragma unroll
  for (int u = 0; u < 5; ++u) { mt[u] = -INFINITY; ut[u] = -INFINITY; }
  for (int b = lane; b < NBI; b += 64) {
    se  += p[b*12 + 0];
    sem += p[b*12 + 1];
    #pragma unroll
    for (int u = 0; u < 5; ++u) { insert5_v(mt, p[b*12 + 2 + u]); insert5_v(ut, p[b*12 + 7 + u]); }
  }
  #pragma unroll
  for (int o = 32; o > 0; o >>= 1) { se += __shfl_xor(se, o, 64); sem += __shfl_xor(sem, o, 64); }
  wave_merge5_v(mt);
  wave_merge5_v(ut);
  if (lane == 0) {
    float nln = 0.f, nun = 0.f;
    #pragma unroll
    for (int u = 0; u < 5; ++u) {
      if (mt[u] > -1e30f) nln += mt[u];
      if (ut[u] > -1e30f) nun += ut[u];
    }
    scores[j]   = nln / nun;
    contrast[j] = sem / se;
  }
}

// ---------------- K5: top-512 selection + loss --------------------------------------
__global__ __launch_bounds__(1024) void k_finalize(const float* __restrict__ scores,
                                                   const float* __restrict__ contrast,
                                                   float* __restrict__ out) {
  __shared__ float sc[N_TGT];
  __shared__ float red[N_TGT];
  const int j = threadIdx.x;
  sc[j] = scores[j];
  __syncthreads();
  float my = sc[j];
  int rank = 0;
  for (int m = 0; m < N_TGT; ++m) {
    float s = sc[m];
    rank += ((s > my) || (s == my && m < j)) ? 1 : 0;
  }
  red[j] = (rank < TOPSEL) ? logf(contrast[j] + LOSS_EPS) : 0.0f;
  __syncthreads();
  for (int s = 512; s > 0; s >>= 1) { if (j < s) red[j] += red[j+s]; __syncthreads(); }
  if (j == 0) out[0] = -red[0] / (float)TOPSEL;
}

// ---------------- launcher ----------------------------------------------------------
extern "C" void kernel_launch(void* const* d_in, const int* in_sizes, int n_in,
                              void* d_out, int out_size, void* d_ws, size_t ws_size,
                              hipStream_t stream) {
  const float* S      = (const float*)d_in[0];
  const int*   labels = (const int*)d_in[1];
  const float* T      = (const float*)d_in[2];
  float* out = (float*)d_out;

  float* ws = (float*)d_ws;
  float* scores    = ws;                                        // 1024
  float* contrastA = scores + N_TGT;                            // 1024
  int*   assigned  = (int*)(contrastA + N_TGT);                 // 1024
  float* p1v       = (float*)(assigned + N_TGT);                // 1024*512*5
  int*   p1i       = (int*)(p1v + (size_t)N_TGT*NBI*5);         // 1024*512*5
  float* p2p       = (float*)(p1i + (size_t)N_TGT*NBI*5);       // 1024*512*12
  unsigned short* Shi = (unsigned short*)(p2p + (size_t)N_TGT*NBI*12);
  unsigned short* Slo = Shi + (size_t)N_SRC*DIM;
  unsigned short* Thi = Slo + (size_t)N_SRC*DIM;
  unsigned short* Tlo = Thi + (size_t)N_TGT*DIM;

  k_norm_split<<<N_TGT/4, 256, 0, stream>>>(T, Thi, Tlo);
  k_norm_split<<<N_SRC/4, 256, 0, stream>>>(S, Shi, Slo);

  k_gemm_fused<1><<<NBI * NBJ, 256, 0, stream>>>(Shi, Slo, Thi, Tlo, labels, assigned, p1v, p1i, p2p);
  k_assign2<<<N_TGT/4, 256, 0, stream>>>(p1v, p1i, labels, assigned);
  k_gemm_fused<2><<<NBI * NBJ, 256, 0, stream>>>(Shi, Slo, Thi, Tlo, labels, assigned, p1v, p1i, p2p);
  k_score2<<<N_TGT/4, 256, 0, stream>>>(p2p, scores, contrastA);
  k_finalize<<<1, 1024, 0, stream>>>(scores, contrastA, out);
}

// Round 5
// 2751.259 us; speedup vs baseline: 1.2642x; 1.2642x over previous
//
#include <hip/hip_runtime.h>
#include <cmath>
#include <cstdint>
#include <cstddef>
#include <climits>

#define N_SRC 65536
#define N_TGT 1024
#define DIM   256
#define TAU_INV (1.0f/0.07f)
#define LOSS_EPS 1e-6f
#define TOPSEL 512
#define NBI (N_SRC/128)     // 512 row-blocks (M-tiles of 128)
#define NBJ (N_TGT/128)     // 8 col-blocks (N-tiles of 128)
#define PANELS 4            // bi-panels per persistent block
#define NGRP (NBI/PANELS)   // 128 groups

typedef __bf16 bf16x8 __attribute__((ext_vector_type(8)));
typedef float  f32x4  __attribute__((ext_vector_type(4)));

// ---------------- bf16 split helpers ------------------------------------------------
__device__ __forceinline__ unsigned short f2bf(float x) {
  unsigned u = __float_as_uint(x);
  unsigned r = (u + 0x7fffu + ((u >> 16) & 1u)) >> 16;
  return (unsigned short)r;
}
__device__ __forceinline__ float bf2f(unsigned short h) {
  return __uint_as_float(((unsigned)h) << 16);
}

// ---------------- top-5 insertion helpers -------------------------------------------
__device__ __forceinline__ void insert5_vi(float v[5], int id[5], float nv, int ni) {
  bool beats_last = (nv > v[4]) || (nv == v[4] && ni < id[4]);
  if (!beats_last) return;
  #pragma unroll
  for (int p = 4; p > 0; --p) {
    bool up = (nv > v[p-1]) || (nv == v[p-1] && ni < id[p-1]);
    if (up) { v[p] = v[p-1]; id[p] = id[p-1]; }
    else    { v[p] = nv; id[p] = ni; return; }
  }
  v[0] = nv; id[0] = ni;
}
__device__ __forceinline__ void insert5_v(float v[5], float nv) {
  if (!(nv > v[4])) return;
  #pragma unroll
  for (int p = 4; p > 0; --p) {
    if (nv > v[p-1]) v[p] = v[p-1];
    else { v[p] = nv; return; }
  }
  v[0] = nv;
}
__device__ __forceinline__ void wave_merge5_vi(float v[5], int id[5]) {
  #pragma unroll
  for (int off = 1; off < 64; off <<= 1) {
    float pv[5]; int pi[5];
    #pragma unroll
    for (int u = 0; u < 5; ++u) {
      pv[u] = __shfl_xor(v[u], off, 64);
      pi[u] = __shfl_xor(id[u], off, 64);
    }
    #pragma unroll
    for (int u = 0; u < 5; ++u) insert5_vi(v, id, pv[u], pi[u]);
  }
}
__device__ __forceinline__ void wave_merge5_v(float v[5]) {
  #pragma unroll
  for (int off = 1; off < 64; off <<= 1) {
    float pv[5];
    #pragma unroll
    for (int u = 0; u < 5; ++u) pv[u] = __shfl_xor(v[u], off, 64);
    #pragma unroll
    for (int u = 0; u < 5; ++u) insert5_v(v, pv[u]);
  }
}

// ---------------- K1: row-normalize + split fp32 -> (hi, lo) bf16 -------------------
__global__ __launch_bounds__(256) void k_norm_split(const float* __restrict__ X,
                                                    unsigned short* __restrict__ hi,
                                                    unsigned short* __restrict__ lo) {
  int wave = threadIdx.x >> 6, lane = threadIdx.x & 63;
  int row  = blockIdx.x * 4 + wave;
  float4 v = reinterpret_cast<const float4*>(X + (size_t)row * DIM)[lane];
  float ss = v.x*v.x + v.y*v.y + v.z*v.z + v.w*v.w;
  #pragma unroll
  for (int o = 32; o > 0; o >>= 1) ss += __shfl_xor(ss, o, 64);
  float r = 1.0f / sqrtf(ss);
  v.x *= r; v.y *= r; v.z *= r; v.w *= r;
  ushort4 h, l;
  h.x = f2bf(v.x); l.x = f2bf(v.x - bf2f(h.x));
  h.y = f2bf(v.y); l.y = f2bf(v.y - bf2f(h.y));
  h.z = f2bf(v.z); l.z = f2bf(v.z - bf2f(h.z));
  h.w = f2bf(v.w); l.w = f2bf(v.w - bf2f(h.w));
  reinterpret_cast<ushort4*>(hi + (size_t)row * DIM)[lane] = h;
  reinterpret_cast<ushort4*>(lo + (size_t)row * DIM)[lane] = l;
}

// ---------------- K2: persistent fused GEMM (m97 dbuf structure, 4 panels/block) ----
// Tile 128x128, BK=32, 4 waves 2x2, 16 indep MFMA/step, K'=768 over segments
// {(Ahi,Bhi),(Alo,Bhi),(Ahi,Blo)}. Each block: fixed bj, loops 4 consecutive bi
// panels (96 K-steps between launches); next panel's first tile prefetched during
// the epilogue. Dedicated 12KB scratch (no staging aliasing). grid d: bj=d>>7,
// grp=d&127; XCD = d%8 = grp%8 -> all 8 bj-blocks of a group share one XCD's L2.
__device__ __forceinline__ void gl_lds(const unsigned short* g, unsigned short* d) {
  __builtin_amdgcn_global_load_lds(
      (const __attribute__((address_space(1))) unsigned int*)g,
      (__attribute__((address_space(3))) unsigned int*)d, 16, 0, 0);
}

template<int PHASE>
__global__ __launch_bounds__(256, 3) void k_gemm_fused(
    const unsigned short* __restrict__ Ahi, const unsigned short* __restrict__ Alo,
    const unsigned short* __restrict__ Bhi, const unsigned short* __restrict__ Blo,
    const int* __restrict__ labels, const int* __restrict__ assigned,
    float* __restrict__ p1v, int* __restrict__ p1i, float* __restrict__ p2p)
{
  __shared__ unsigned short bufA[2 * 128 * 32];   // [As|Bs] even tiles (16KB)
  __shared__ unsigned short bufB[2 * 128 * 32];   // odd tiles (16KB)
  __shared__ float scr[3072];                     // epilogue scratch (12KB)
  __shared__ int lab_s[512];
  __shared__ int asg_s[128];

  const int tid  = threadIdx.x;
  const int lane = tid & 63;
  const int w    = tid >> 6;
  const int wm   = w & 1;
  const int wn   = w >> 1;

  const int d   = blockIdx.x;       // grid = NBJ*NGRP = 1024
  const int bj  = d >> 7;           // 0..7
  const int grp = d & 127;          // 0..127 (XCD = grp%8)
  const int j0  = bj << 7;
  const int i0  = (grp * PANELS) << 7;   // first row of this block's 4 panels

  if constexpr (PHASE == 2) {
    lab_s[tid]       = labels[i0 + tid];
    lab_s[tid + 256] = labels[i0 + tid + 256];
    if (tid < 128) asg_s[tid] = assigned[j0 + tid];
  }

  const int srow = (w << 5) + (lane >> 2);
  const int scol = (lane & 3) << 3;
  const unsigned short* gAh = Ahi + (size_t)(i0 + srow) * DIM + scol;
  const unsigned short* gAl = Alo + (size_t)(i0 + srow) * DIM + scol;
  const unsigned short* gBh = Bhi + (size_t)(j0 + srow) * DIM + scol;
  const unsigned short* gBl = Blo + (size_t)(j0 + srow) * DIM + scol;

  auto stage = [&](const unsigned short* gA, const unsigned short* gB, int kc,
                   unsigned short* s) {
    gl_lds(gA + kc,          s + (w << 5) * 32);
    gl_lds(gA + kc + 16*DIM, s + ((w << 5) + 16) * 32);
    gl_lds(gB + kc,          s + 128*32 + (w << 5) * 32);
    gl_lds(gB + kc + 16*DIM, s + 128*32 + ((w << 5) + 16) * 32);
  };

  const int fr = lane & 15;
  const int fq = lane >> 4;
  const int fk = fq << 3;

  stage(gAh, gBh, 0, bufA);
  __syncthreads();

  #pragma unroll 1
  for (int ib = 0; ib < PANELS; ++ib) {
    const int i0c = i0 + (ib << 7);

    f32x4 acc[4][4];
    #pragma unroll
    for (int a = 0; a < 4; ++a)
      #pragma unroll
      for (int b = 0; b < 4; ++b) acc[a][b] = f32x4{0.f, 0.f, 0.f, 0.f};

    #pragma unroll
    for (int t = 0; t < 24; ++t) {
      const unsigned short* cur = (t & 1) ? bufB : bufA;
      unsigned short*       nxt = (t & 1) ? bufA : bufB;
      if (t < 23) {
        const int tn = t + 1, sg = tn >> 3, kc = (tn & 7) << 5;
        stage(sg == 1 ? gAl : gAh, sg == 2 ? gBl : gBh, kc, nxt);
      } else if (ib < PANELS - 1) {
        stage(gAh + 128*DIM, gBh, 0, nxt);   // prefetch next panel's first tile
      }
      const unsigned short* As = cur;
      const unsigned short* Bs = cur + 128*32;
      bf16x8 a[4], b[4];
      #pragma unroll
      for (int rf = 0; rf < 4; ++rf)
        a[rf] = *(const bf16x8*)&As[((wm << 6) + (rf << 4) + fr) * 32 + fk];
      #pragma unroll
      for (int cf = 0; cf < 4; ++cf)
        b[cf] = *(const bf16x8*)&Bs[((wn << 6) + (cf << 4) + fr) * 32 + fk];
      #pragma unroll
      for (int rf = 0; rf < 4; ++rf)
        #pragma unroll
        for (int cf = 0; cf < 4; ++cf)
          acc[rf][cf] = __builtin_amdgcn_mfma_f32_16x16x32_bf16(a[rf], b[cf], acc[rf][cf], 0, 0, 0);
      __syncthreads();
    }

    // ---- epilogue for panel ib. acc map: col n = wn*64+cf*16+fr; row m = wm*64+rf*16+fq*4+reg
    if constexpr (PHASE == 1) {
      float* ep_v = scr;                                 // [2][128][5]
      int*   ep_i = reinterpret_cast<int*>(scr) + 1280;  // [2][128][5]
      #pragma unroll
      for (int cf = 0; cf < 4; ++cf) {
        float tv[5]; int ti[5];
        #pragma unroll
        for (int u = 0; u < 5; ++u) { tv[u] = -INFINITY; ti[u] = INT_MAX; }
        #pragma unroll
        for (int rf = 0; rf < 4; ++rf) {
          const int mb = i0c + (wm << 6) + (rf << 4) + (fq << 2);
          #pragma unroll
          for (int r = 0; r < 4; ++r) insert5_vi(tv, ti, acc[rf][cf][r], mb + r);
        }
        #pragma unroll
        for (int off = 16; off < 64; off <<= 1) {
          float pv[5]; int pi[5];
          #pragma unroll
          for (int u = 0; u < 5; ++u) { pv[u] = __shfl_xor(tv[u], off, 64); pi[u] = __shfl_xor(ti[u], off, 64); }
          #pragma unroll
          for (int u = 0; u < 5; ++u) insert5_vi(tv, ti, pv[u], pi[u]);
        }
        if (lane < 16) {
          const int col = (wn << 6) + (cf << 4) + lane;
          #pragma unroll
          for (int u = 0; u < 5; ++u) { ep_v[(wm*128 + col)*5 + u] = tv[u]; ep_i[(wm*128 + col)*5 + u] = ti[u]; }
        }
      }
      __syncthreads();
      if (tid < 128) {
        float v[5]; int id[5];
        #pragma unroll
        for (int u = 0; u < 5; ++u) { v[u] = -INFINITY; id[u] = INT_MAX; }
        #pragma unroll
        for (int h = 0; h < 2; ++h)
          #pragma unroll
          for (int u = 0; u < 5; ++u)
            insert5_vi(v, id, ep_v[(h*128 + tid)*5 + u], ep_i[(h*128 + tid)*5 + u]);
        const size_t o = ((size_t)(j0 + tid) * NBI + (grp * PANELS + ib)) * 5;
        #pragma unroll
        for (int u = 0; u < 5; ++u) { p1v[o+u] = v[u]; p1i[o+u] = id[u]; }
      }
    } else {
      float* ep = scr;                                   // [2][128][12]
      #pragma unroll
      for (int cf = 0; cf < 4; ++cf) {
        const int col = (wn << 6) + (cf << 4) + fr;
        const int asg = asg_s[col];
        float se = 0.f, sem = 0.f;
        float mt[5], ut[5];
        #pragma unroll
        for (int u = 0; u < 5; ++u) { mt[u] = -INFINITY; ut[u] = -INFINITY; }
        #pragma unroll
        for (int rf = 0; rf < 4; ++rf) {
          const int mb = (ib << 7) + (wm << 6) + (rf << 4) + (fq << 2);
          #pragma unroll
          for (int r = 0; r < 4; ++r) {
            const float val = acc[rf][cf][r];
            const float e = __expf(val * TAU_INV);
            se += e;
            if (lab_s[mb + r] == asg) { sem += e; insert5_v(mt, val); }
            else insert5_v(ut, val);
          }
        }
        #pragma unroll
        for (int off = 16; off < 64; off <<= 1) {
          se  += __shfl_xor(se,  off, 64);
          sem += __shfl_xor(sem, off, 64);
          float pm[5], pu[5];
          #pragma unroll
          for (int u = 0; u < 5; ++u) { pm[u] = __shfl_xor(mt[u], off, 64); pu[u] = __shfl_xor(ut[u], off, 64); }
          #pragma unroll
          for (int u = 0; u < 5; ++u) { insert5_v(mt, pm[u]); insert5_v(ut, pu[u]); }
        }
        if (lane < 16) {
          float* dst = ep + (wm*128 + col) * 12;
          dst[0] = se; dst[1] = sem;
          #pragma unroll
          for (int u = 0; u < 5; ++u) { dst[2+u] = mt[u]; dst[7+u] = ut[u]; }
        }
      }
      __syncthreads();
      if (tid < 128) {
        const float* a = ep + (size_t)tid * 12;
        const float* b = ep + (size_t)(128 + tid) * 12;
        float se = a[0] + b[0], sem = a[1] + b[1];
        float mt[5], ut[5];
        #pragma unroll
        for (int u = 0; u < 5; ++u) { mt[u] = -INFINITY; ut[u] = -INFINITY; }
        #pragma unroll
        for (int u = 0; u < 5; ++u) {
          insert5_v(mt, a[2+u]); insert5_v(mt, b[2+u]);
          insert5_v(ut, a[7+u]); insert5_v(ut, b[7+u]);
        }
        const size_t o = ((size_t)(j0 + tid) * NBI + (grp * PANELS + ib)) * 12;
        p2p[o+0] = se; p2p[o+1] = sem;
        #pragma unroll
        for (int u = 0; u < 5; ++u) { p2p[o+2+u] = mt[u]; p2p[o+7+u] = ut[u]; }
      }
    }

    gAh += 128*DIM;   // advance to next panel
    gAl += 128*DIM;
  }
}

// ---------------- K3: merge row-block top-5s -> assigned label per column -----------
__global__ __launch_bounds__(256) void k_assign2(const float* __restrict__ p1v,
                                                 const int* __restrict__ p1i,
                                                 const int* __restrict__ labels,
                                                 int* __restrict__ assigned) {
  const int w = threadIdx.x >> 6, lane = threadIdx.x & 63;
  const int j = blockIdx.x * 4 + w;
  const float* pv = p1v + (size_t)j * NBI * 5;
  const int*   pi = p1i + (size_t)j * NBI * 5;
  float v[5]; int id[5];
  #pragma unroll
  for (int u = 0; u < 5; ++u) { v[u] = -INFINITY; id[u] = INT_MAX; }
  for (int b = lane; b < NBI; b += 64) {
    #pragma unroll
    for (int u = 0; u < 5; ++u) insert5_vi(v, id, pv[b*5 + u], pi[b*5 + u]);
  }
  wave_merge5_vi(v, id);
  if (lane == 0) {
    int lab[5];
    #pragma unroll
    for (int a = 0; a < 5; ++a) lab[a] = labels[id[a]];
    int bestSc = INT_MIN, bestA = 0;
    #pragma unroll
    for (int a = 0; a < 5; ++a) {
      int cnt = 0;
      #pragma unroll
      for (int b = 0; b < 5; ++b) cnt += (lab[b] == lab[a]) ? 1 : 0;
      int sc = cnt * 1000000 - lab[a];
      if (sc > bestSc) { bestSc = sc; bestA = a; }
    }
    assigned[j] = lab[bestA];
  }
}

// ---------------- K4: merge row-block stats -> scores, contrast ---------------------
__global__ __launch_bounds__(256) void k_score2(const float* __restrict__ p2p,
                                                float* __restrict__ scores,
                                                float* __restrict__ contrast) {
  const int w = threadIdx.x >> 6, lane = threadIdx.x & 63;
  const int j = blockIdx.x * 4 + w;
  const float* p = p2p + (size_t)j * NBI * 12;
  float se = 0.f, sem = 0.f;
  float mt[5], ut[5];
  #pragma unroll
  for (int u = 0; u < 5; ++u) { mt[u] = -INFINITY; ut[u] = -INFINITY; }
  for (int b = lane; b < NBI; b += 64) {
    se  += p[b*12 + 0];
    sem += p[b*12 + 1];
    #pragma unroll
    for (int u = 0; u < 5; ++u) { insert5_v(mt, p[b*12 + 2 + u]); insert5_v(ut, p[b*12 + 7 + u]); }
  }
  #pragma unroll
  for (int o = 32; o > 0; o >>= 1) { se += __shfl_xor(se, o, 64); sem += __shfl_xor(sem, o, 64); }
  wave_merge5_v(mt);
  wave_merge5_v(ut);
  if (lane == 0) {
    float nln = 0.f, nun = 0.f;
    #pragma unroll
    for (int u = 0; u < 5; ++u) {
      if (mt[u] > -1e30f) nln += mt[u];
      if (ut[u] > -1e30f) nun += ut[u];
    }
    scores[j]   = nln / nun;
    contrast[j] = sem / se;
  }
}

// ---------------- K5: top-512 selection + loss --------------------------------------
__global__ __launch_bounds__(1024) void k_finalize(const float* __restrict__ scores,
                                                   const float* __restrict__ contrast,
                                                   float* __restrict__ out) {
  __shared__ float sc[N_TGT];
  __shared__ float red[N_TGT];
  const int j = threadIdx.x;
  sc[j] = scores[j];
  __syncthreads();
  float my = sc[j];
  int rank = 0;
  for (int m = 0; m < N_TGT; ++m) {
    float s = sc[m];
    rank += ((s > my) || (s == my && m < j)) ? 1 : 0;
  }
  red[j] = (rank < TOPSEL) ? logf(contrast[j] + LOSS_EPS) : 0.0f;
  __syncthreads();
  for (int s = 512; s > 0; s >>= 1) { if (j < s) red[j] += red[j+s]; __syncthreads(); }
  if (j == 0) out[0] = -red[0] / (float)TOPSEL;
}

// ---------------- launcher ----------------------------------------------------------
extern "C" void kernel_launch(void* const* d_in, const int* in_sizes, int n_in,
                              void* d_out, int out_size, void* d_ws, size_t ws_size,
                              hipStream_t stream) {
  const float* S      = (const float*)d_in[0];
  const int*   labels = (const int*)d_in[1];
  const float* T      = (const float*)d_in[2];
  float* out = (float*)d_out;

  float* ws = (float*)d_ws;
  float* scores    = ws;                                        // 1024
  float* contrastA = scores + N_TGT;                            // 1024
  int*   assigned  = (int*)(contrastA + N_TGT);                 // 1024
  float* p1v       = (float*)(assigned + N_TGT);                // 1024*512*5
  int*   p1i       = (int*)(p1v + (size_t)N_TGT*NBI*5);         // 1024*512*5
  float* p2p       = (float*)(p1i + (size_t)N_TGT*NBI*5);       // 1024*512*12
  unsigned short* Shi = (unsigned short*)(p2p + (size_t)N_TGT*NBI*12);
  unsigned short* Slo = Shi + (size_t)N_SRC*DIM;
  unsigned short* Thi = Slo + (size_t)N_SRC*DIM;
  unsigned short* Tlo = Thi + (size_t)N_TGT*DIM;

  k_norm_split<<<N_TGT/4, 256, 0, stream>>>(T, Thi, Tlo);
  k_norm_split<<<N_SRC/4, 256, 0, stream>>>(S, Shi, Slo);

  k_gemm_fused<1><<<NBJ * NGRP, 256, 0, stream>>>(Shi, Slo, Thi, Tlo, labels, assigned, p1v, p1i, p2p);
  k_assign2<<<N_TGT/4, 256, 0, stream>>>(p1v, p1i, labels, assigned);
  k_gemm_fused<2><<<NBJ * NGRP, 256, 0, stream>>>(Shi, Slo, Thi, Tlo, labels, assigned, p1v, p1i, p2p);
  k_score2<<<N_TGT/4, 256, 0, stream>>>(p2p, scores, contrastA);
  k_finalize<<<1, 1024, 0, stream>>>(scores, contrastA, out);
}

// Round 6
// 1235.834 us; speedup vs baseline: 2.8143x; 2.2262x over previous
//
#include <hip/hip_runtime.h>
#include <cmath>
#include <cstdint>
#include <cstddef>
#include <climits>

#define N_SRC 65536
#define N_TGT 1024
#define DIM   256
#define TAU_INV (1.0f/0.07f)
#define LOSS_EPS 1e-6f
#define TOPSEL 512
#define NSLICE 8
#define SLICE_ELEMS (N_SRC / NSLICE)   // 8192
#define N_CLASSES 345

typedef __bf16 bf16x8 __attribute__((ext_vector_type(8)));
typedef float  f32x4  __attribute__((ext_vector_type(4)));

// ---------------- bf16 split helpers ------------------------------------------------
__device__ __forceinline__ unsigned short f2bf(float x) {
  unsigned u = __float_as_uint(x);
  unsigned r = (u + 0x7fffu + ((u >> 16) & 1u)) >> 16;
  return (unsigned short)r;
}
__device__ __forceinline__ float bf2f(unsigned short h) {
  return __uint_as_float(((unsigned)h) << 16);
}

// ---------------- top-5 insertion helpers -------------------------------------------
__device__ __forceinline__ void insert5_vi(float v[5], int id[5], float nv, int ni) {
  bool beats_last = (nv > v[4]) || (nv == v[4] && ni < id[4]);
  if (!beats_last) return;
  #pragma unroll
  for (int p = 4; p > 0; --p) {
    bool up = (nv > v[p-1]) || (nv == v[p-1] && ni < id[p-1]);
    if (up) { v[p] = v[p-1]; id[p] = id[p-1]; }
    else    { v[p] = nv; id[p] = ni; return; }
  }
  v[0] = nv; id[0] = ni;
}
__device__ __forceinline__ void insert5_v(float v[5], float nv) {
  if (!(nv > v[4])) return;
  #pragma unroll
  for (int p = 4; p > 0; --p) {
    if (nv > v[p-1]) v[p] = v[p-1];
    else { v[p] = nv; return; }
  }
  v[0] = nv;
}
__device__ __forceinline__ void wave_merge5_vi(float v[5], int id[5]) {
  #pragma unroll
  for (int off = 1; off < 64; off <<= 1) {
    float pv[5]; int pi[5];
    #pragma unroll
    for (int u = 0; u < 5; ++u) {
      pv[u] = __shfl_xor(v[u], off, 64);
      pi[u] = __shfl_xor(id[u], off, 64);
    }
    #pragma unroll
    for (int u = 0; u < 5; ++u) insert5_vi(v, id, pv[u], pi[u]);
  }
}
__device__ __forceinline__ void wave_merge5_v(float v[5]) {
  #pragma unroll
  for (int off = 1; off < 64; off <<= 1) {
    float pv[5];
    #pragma unroll
    for (int u = 0; u < 5; ++u) pv[u] = __shfl_xor(v[u], off, 64);
    #pragma unroll
    for (int u = 0; u < 5; ++u) insert5_v(v, pv[u]);
  }
}

// ---------------- preprocessing: counting sort of rows by label ---------------------
__global__ __launch_bounds__(512) void k_zero(int* __restrict__ hist) {
  if (threadIdx.x < N_CLASSES) hist[threadIdx.x] = 0;
}
__global__ __launch_bounds__(256) void k_hist(const int* __restrict__ labels,
                                              int* __restrict__ hist) {
  int i = blockIdx.x * 256 + threadIdx.x;
  atomicAdd(&hist[labels[i]], 1);
}
__global__ __launch_bounds__(64) void k_scan(const int* __restrict__ hist,
                                             int* __restrict__ start,
                                             int* __restrict__ cursor) {
  if (threadIdx.x == 0) {
    int acc = 0;
    for (int c = 0; c < N_CLASSES; ++c) {
      start[c] = acc; cursor[c] = acc; acc += hist[c];
    }
    start[N_CLASSES] = acc;
  }
}
__global__ __launch_bounds__(256) void k_perm(const int* __restrict__ labels,
                                              int* __restrict__ cursor,
                                              int* __restrict__ g,
                                              int* __restrict__ sortedLab) {
  int i = blockIdx.x * 256 + threadIdx.x;
  int l = labels[i];
  int slot = atomicAdd(&cursor[l], 1);
  g[slot] = i;
  sortedLab[slot] = l;
}

// ---------------- K1: row-normalize + split fp32 -> (hi, lo) bf16 -------------------
// one wave per OUTPUT row; optional gather index (src row = g[row])
__global__ __launch_bounds__(256) void k_norm_split(const float* __restrict__ X,
                                                    const int* __restrict__ g,
                                                    unsigned short* __restrict__ hi,
                                                    unsigned short* __restrict__ lo) {
  int wave = threadIdx.x >> 6, lane = threadIdx.x & 63;
  int row  = blockIdx.x * 4 + wave;
  int src  = g ? g[row] : row;
  float4 v = reinterpret_cast<const float4*>(X + (size_t)src * DIM)[lane];
  float ss = v.x*v.x + v.y*v.y + v.z*v.z + v.w*v.w;
  #pragma unroll
  for (int o = 32; o > 0; o >>= 1) ss += __shfl_xor(ss, o, 64);
  float r = 1.0f / sqrtf(ss);
  v.x *= r; v.y *= r; v.z *= r; v.w *= r;
  ushort4 h, l;
  h.x = f2bf(v.x); l.x = f2bf(v.x - bf2f(h.x));
  h.y = f2bf(v.y); l.y = f2bf(v.y - bf2f(h.y));
  h.z = f2bf(v.z); l.z = f2bf(v.z - bf2f(h.z));
  h.w = f2bf(v.w); l.w = f2bf(v.w - bf2f(h.w));
  reinterpret_cast<ushort4*>(hi + (size_t)row * DIM)[lane] = h;
  reinterpret_cast<ushort4*>(lo + (size_t)row * DIM)[lane] = l;
}

// ---------------- K2: split-bf16 MFMA GEMM (R0's measured-fastest variant) ----------
// 128x128 tile, BK=32 bf16, 4 waves 2x2, each wave 4x4 frags of 16x16x32.
// 3 MFMAs per frag pair: hi*hi + hi*lo + lo*hi (lo*lo dropped, ~2^-16 rel).
// Inputs pre-normalized -> no sinv epilogue. simT[j][i] = s_i . t_j.
__device__ __forceinline__ void gl_lds(const unsigned short* g, unsigned short* d) {
  __builtin_amdgcn_global_load_lds(
      (const __attribute__((address_space(1))) unsigned int*)g,
      (__attribute__((address_space(3))) unsigned int*)d, 16, 0, 0);
}

__global__ __launch_bounds__(256) void k_gemm(
    const unsigned short* __restrict__ Ahi, const unsigned short* __restrict__ Alo,
    const unsigned short* __restrict__ Bhi, const unsigned short* __restrict__ Blo,
    float* __restrict__ simT, int j_off)
{
  __shared__ unsigned short As_hi[128*32];
  __shared__ unsigned short As_lo[128*32];
  __shared__ unsigned short Bs_hi[128*32];
  __shared__ unsigned short Bs_lo[128*32];

  const int tid  = threadIdx.x;
  const int lane = tid & 63;
  const int w    = tid >> 6;       // wave 0..3
  const int wm   = w & 1;          // src-dim half
  const int wn   = w >> 1;         // tgt-dim half
  const int i0   = blockIdx.x * 128;
  const int j0g  = j_off + blockIdx.y * 128;   // global target row (for B loads)
  const int j0l  = blockIdx.y * 128;           // chunk-local (for simT)

  f32x4 acc[4][4];
  #pragma unroll
  for (int a = 0; a < 4; ++a)
    #pragma unroll
    for (int b = 0; b < 4; ++b) acc[a][b] = f32x4{0.f, 0.f, 0.f, 0.f};

  const int srow = (w << 5) + (lane >> 2);
  const int scol = (lane & 3) << 3;             // element offset (8 bf16 = 16 B)
  const unsigned short* gAh = Ahi + (size_t)(i0  + srow) * DIM + scol;
  const unsigned short* gAl = Alo + (size_t)(i0  + srow) * DIM + scol;
  const unsigned short* gBh = Bhi + (size_t)(j0g + srow) * DIM + scol;
  const unsigned short* gBl = Blo + (size_t)(j0g + srow) * DIM + scol;
  unsigned short* dA0  = &As_hi[(w << 5) * 32];
  unsigned short* dA1  = &As_hi[((w << 5) + 16) * 32];
  unsigned short* dB0  = &Bs_hi[(w << 5) * 32];
  unsigned short* dB1  = &Bs_hi[((w << 5) + 16) * 32];
  unsigned short* dA0l = &As_lo[(w << 5) * 32];
  unsigned short* dA1l = &As_lo[((w << 5) + 16) * 32];
  unsigned short* dB0l = &Bs_lo[(w << 5) * 32];
  unsigned short* dB1l = &Bs_lo[((w << 5) + 16) * 32];

  const int fr = lane & 15;
  const int fk = (lane >> 4) << 3;

  for (int k0 = 0; k0 < DIM; k0 += 32) {
    __syncthreads();
    gl_lds(gAh + k0,           dA0);
    gl_lds(gAh + k0 + 16*DIM,  dA1);
    gl_lds(gAl + k0,           dA0l);
    gl_lds(gAl + k0 + 16*DIM,  dA1l);
    gl_lds(gBh + k0,           dB0);
    gl_lds(gBh + k0 + 16*DIM,  dB1);
    gl_lds(gBl + k0,           dB0l);
    gl_lds(gBl + k0 + 16*DIM,  dB1l);
    __syncthreads();

    bf16x8 ah[4], al[4], bh[4], bl[4];
    #pragma unroll
    for (int rf = 0; rf < 4; ++rf) {
      int r = ((wm << 6) + (rf << 4) + fr) * 32 + fk;
      ah[rf] = *(const bf16x8*)&As_hi[r];
      al[rf] = *(const bf16x8*)&As_lo[r];
    }
    #pragma unroll
    for (int cf = 0; cf < 4; ++cf) {
      int r = ((wn << 6) + (cf << 4) + fr) * 32 + fk;
      bh[cf] = *(const bf16x8*)&Bs_hi[r];
      bl[cf] = *(const bf16x8*)&Bs_lo[r];
    }
    #pragma unroll
    for (int rf = 0; rf < 4; ++rf)
      #pragma unroll
      for (int cf = 0; cf < 4; ++cf) {
        acc[rf][cf] = __builtin_amdgcn_mfma_f32_16x16x32_bf16(ah[rf], bh[cf], acc[rf][cf], 0, 0, 0);
        acc[rf][cf] = __builtin_amdgcn_mfma_f32_16x16x32_bf16(ah[rf], bl[cf], acc[rf][cf], 0, 0, 0);
        acc[rf][cf] = __builtin_amdgcn_mfma_f32_16x16x32_bf16(al[rf], bh[cf], acc[rf][cf], 0, 0, 0);
      }
  }

  // epilogue: D[m][n] lane mapping n = lane&15, m = (lane>>4)*4 + reg
  #pragma unroll
  for (int rf = 0; rf < 4; ++rf) {
    const int m_base = (wm << 6) + (rf << 4) + ((lane >> 4) << 2);
    #pragma unroll
    for (int cf = 0; cf < 4; ++cf) {
      const int n = (wn << 6) + (cf << 4) + (lane & 15);
      *reinterpret_cast<float4*>(&simT[(size_t)(j0l + n) * N_SRC + i0 + m_base]) =
          make_float4(acc[rf][cf][0], acc[rf][cf][1], acc[rf][cf][2], acc[rf][cf][3]);
    }
  }
}

// ---------------- K3: per-slice top-5 (val,idx) + sum-exp partials ------------------
__global__ __launch_bounds__(256) void k_part1se(const float* __restrict__ simT,
                                                 float* __restrict__ p1v, int* __restrict__ p1i,
                                                 float* __restrict__ pse, int j_off) {
  const int s    = blockIdx.x;     // slice 0..7
  const int jloc = blockIdx.y;
  const int tid  = threadIdx.x;
  const int lane = tid & 63, w = tid >> 6;
  const float4* row = reinterpret_cast<const float4*>(simT + (size_t)jloc * N_SRC)
                      + s * (SLICE_ELEMS/4) + tid;
  float tv[5]; int tix[5]; float sse = 0.f;
  #pragma unroll
  for (int u = 0; u < 5; ++u) { tv[u] = -INFINITY; tix[u] = INT_MAX; }
  const int base = s * SLICE_ELEMS + tid * 4;
  #pragma unroll
  for (int t = 0; t < 8; ++t) {
    float4 v = row[t * 256];
    int bi = base + t * 1024;
    insert5_vi(tv, tix, v.x, bi);
    insert5_vi(tv, tix, v.y, bi + 1);
    insert5_vi(tv, tix, v.z, bi + 2);
    insert5_vi(tv, tix, v.w, bi + 3);
    sse += __expf(v.x * TAU_INV) + __expf(v.y * TAU_INV)
         + __expf(v.z * TAU_INV) + __expf(v.w * TAU_INV);
  }
  wave_merge5_vi(tv, tix);
  #pragma unroll
  for (int o = 32; o > 0; o >>= 1) sse += __shfl_xor(sse, o, 64);
  __shared__ float wv[4*5]; __shared__ int wi[4*5]; __shared__ float wse[4];
  if (lane == 0) {
    #pragma unroll
    for (int u = 0; u < 5; ++u) { wv[w*5+u] = tv[u]; wi[w*5+u] = tix[u]; }
    wse[w] = sse;
  }
  __syncthreads();
  if (tid == 0) {
    float v3[5]; int i3[5];
    #pragma unroll
    for (int u = 0; u < 5; ++u) { v3[u] = -INFINITY; i3[u] = INT_MAX; }
    for (int c = 0; c < 20; ++c) insert5_vi(v3, i3, wv[c], wi[c]);
    const size_t o = ((size_t)(j_off + jloc) * NSLICE + s) * 5;
    #pragma unroll
    for (int u = 0; u < 5; ++u) { p1v[o+u] = v3[u]; p1i[o+u] = i3[u]; }
    pse[(size_t)(j_off + jloc) * NSLICE + s] = wse[0]+wse[1]+wse[2]+wse[3];
  }
}

// ---------------- K4: merge slices -> assigned label per column ---------------------
__global__ __launch_bounds__(64) void k_assign(const float* __restrict__ p1v,
                                               const int* __restrict__ p1i,
                                               const int* __restrict__ sortedLab,
                                               int* __restrict__ assigned, int j_off) {
  const int j = j_off + blockIdx.x * 64 + threadIdx.x;
  float v[5]; int id[5];
  #pragma unroll
  for (int u = 0; u < 5; ++u) { v[u] = -INFINITY; id[u] = INT_MAX; }
  for (int c = 0; c < NSLICE * 5; ++c)
    insert5_vi(v, id, p1v[(size_t)j * NSLICE * 5 + c], p1i[(size_t)j * NSLICE * 5 + c]);
  int lab[5];
  #pragma unroll
  for (int a = 0; a < 5; ++a) lab[a] = sortedLab[id[a]];
  int bestSc = INT_MIN, bestA = 0;
  #pragma unroll
  for (int a = 0; a < 5; ++a) {
    int c = 0;
    #pragma unroll
    for (int b = 0; b < 5; ++b) c += (lab[b] == lab[a]) ? 1 : 0;
    int sc = c * 1000000 - lab[a];
    if (sc > bestSc) { bestSc = sc; bestA = a; }
  }
  assigned[j] = lab[bestA];
}

// ---------------- K5: targeted pass2 — stream only slices containing matched range --
// Rows sorted by class: matched set = [start[asg], start[asg+1]) in <=2 slices.
// sem/mt from streamed range; ut from streamed unmatched + stored top5s of other
// slices (which contain no matched rows); se = sum of pse. Score inline.
__global__ __launch_bounds__(256) void k_part2n(const float* __restrict__ simT,
                                                const int* __restrict__ assigned,
                                                const int* __restrict__ start,
                                                const float* __restrict__ p1v,
                                                const float* __restrict__ pse,
                                                float* __restrict__ scores,
                                                float* __restrict__ contrast, int j_off) {
  const int jloc = blockIdx.x;
  const int j    = j_off + jloc;
  const int tid  = threadIdx.x;
  const int lane = tid & 63, w = tid >> 6;
  const int asg  = assigned[j];
  const int a    = start[asg];
  const int b    = start[asg + 1];
  const int s0   = a >> 13;                 // /8192
  const int s1   = (b - 1) >> 13;

  float mt[5], ut[5]; float sem = 0.f;
  #pragma unroll
  for (int u = 0; u < 5; ++u) { mt[u] = -INFINITY; ut[u] = -INFINITY; }

  const float4* col = reinterpret_cast<const float4*>(simT + (size_t)jloc * N_SRC);
  for (int s = s0; s <= s1; ++s) {
    const int base = s * SLICE_ELEMS + tid * 4;
    const float4* row = col + s * (SLICE_ELEMS/4) + tid;
    #pragma unroll
    for (int t = 0; t < 8; ++t) {
      float4 v = row[t * 256];
      int i = base + t * 1024;
      if (i   >= a && i   < b) { sem += __expf(v.x * TAU_INV); insert5_v(mt, v.x); } else insert5_v(ut, v.x);
      if (i+1 >= a && i+1 < b) { sem += __expf(v.y * TAU_INV); insert5_v(mt, v.y); } else insert5_v(ut, v.y);
      if (i+2 >= a && i+2 < b) { sem += __expf(v.z * TAU_INV); insert5_v(mt, v.z); } else insert5_v(ut, v.z);
      if (i+3 >= a && i+3 < b) { sem += __expf(v.w * TAU_INV); insert5_v(mt, v.w); } else insert5_v(ut, v.w);
    }
  }
  #pragma unroll
  for (int o = 32; o > 0; o >>= 1) sem += __shfl_xor(sem, o, 64);
  wave_merge5_v(mt);
  wave_merge5_v(ut);
  __shared__ float wmt[4*5], wut[4*5], wsm[4];
  if (lane == 0) {
    #pragma unroll
    for (int u = 0; u < 5; ++u) { wmt[w*5+u] = mt[u]; wut[w*5+u] = ut[u]; }
    wsm[w] = sem;
  }
  __syncthreads();
  if (tid == 0) {
    float m3[5], u3[5];
    #pragma unroll
    for (int u = 0; u < 5; ++u) { m3[u] = -INFINITY; u3[u] = -INFINITY; }
    for (int c = 0; c < 20; ++c) { insert5_v(m3, wmt[c]); insert5_v(u3, wut[c]); }
    // fold stored per-slice top5s for slices outside [s0,s1] (no matched rows there)
    float se = 0.f;
    for (int s = 0; s < NSLICE; ++s) {
      se += pse[(size_t)j * NSLICE + s];
      if (s >= s0 && s <= s1) continue;
      const float* pv = p1v + ((size_t)j * NSLICE + s) * 5;
      #pragma unroll
      for (int u = 0; u < 5; ++u) insert5_v(u3, pv[u]);
    }
    float smm = wsm[0]+wsm[1]+wsm[2]+wsm[3];
    float nln = 0.f, nun = 0.f;
    #pragma unroll
    for (int u = 0; u < 5; ++u) {
      if (m3[u] > -1e30f) nln += m3[u];
      if (u3[u] > -1e30f) nun += u3[u];
    }
    scores[j]   = nln / nun;
    contrast[j] = smm / se;
  }
}

// ---------------- K6: top-512 selection + loss --------------------------------------
__global__ __launch_bounds__(1024) void k_finalize(const float* __restrict__ scores,
                                                   const float* __restrict__ contrast,
                                                   float* __restrict__ out) {
  __shared__ float sc[N_TGT];
  __shared__ float red[N_TGT];
  const int j = threadIdx.x;
  sc[j] = scores[j];
  __syncthreads();
  float my = sc[j];
  int rank = 0;
  for (int m = 0; m < N_TGT; ++m) {
    float s = sc[m];
    rank += ((s > my) || (s == my && m < j)) ? 1 : 0;
  }
  red[j] = (rank < TOPSEL) ? logf(contrast[j] + LOSS_EPS) : 0.0f;
  __syncthreads();
  for (int s = 512; s > 0; s >>= 1) { if (j < s) red[j] += red[j+s]; __syncthreads(); }
  if (j == 0) out[0] = -red[0] / (float)TOPSEL;
}

// ---------------- launcher ----------------------------------------------------------
extern "C" void kernel_launch(void* const* d_in, const int* in_sizes, int n_in,
                              void* d_out, int out_size, void* d_ws, size_t ws_size,
                              hipStream_t stream) {
  const float* S      = (const float*)d_in[0];
  const int*   labels = (const int*)d_in[1];
  const float* T      = (const float*)d_in[2];
  float* out = (float*)d_out;

  float* ws = (float*)d_ws;
  float* scores    = ws;                               // 1024
  float* contrastA = scores + N_TGT;                   // 1024
  int*   assigned  = (int*)(contrastA + N_TGT);        // 1024
  float* p1v       = (float*)(assigned + N_TGT);       // 1024*8*5
  int*   p1i       = (int*)(p1v + N_TGT*NSLICE*5);     // 1024*8*5
  float* pse       = (float*)(p1i + N_TGT*NSLICE*5);   // 1024*8
  int*   hist      = (int*)(pse + N_TGT*NSLICE);       // 345
  int*   startArr  = hist + N_CLASSES;                 // 346
  int*   cursor    = startArr + (N_CLASSES + 1);       // 345
  int*   gidx      = cursor + N_CLASSES;               // 65536
  int*   sortedLab = gidx + N_SRC;                     // 65536
  unsigned short* Shi = (unsigned short*)(sortedLab + N_SRC);
  unsigned short* Slo = Shi + (size_t)N_SRC*DIM;
  unsigned short* Thi = Slo + (size_t)N_SRC*DIM;
  unsigned short* Tlo = Thi + (size_t)N_TGT*DIM;
  float* simbuf       = (float*)(Tlo + (size_t)N_TGT*DIM);

  size_t head  = (size_t)(simbuf - ws);
  size_t avail = (ws_size / 4 > head) ? (ws_size / 4 - head) : 0;
  int cols = 128;
  if      (avail >= (size_t)1024 * N_SRC) cols = 1024;
  else if (avail >= (size_t)512  * N_SRC) cols = 512;
  else if (avail >= (size_t)256  * N_SRC) cols = 256;

  // preprocessing: counting sort of source rows by label
  k_zero<<<1, 512, 0, stream>>>(hist);
  k_hist<<<N_SRC/256, 256, 0, stream>>>(labels, hist);
  k_scan<<<1, 64, 0, stream>>>(hist, startArr, cursor);
  k_perm<<<N_SRC/256, 256, 0, stream>>>(labels, cursor, gidx, sortedLab);

  k_norm_split<<<N_TGT/4, 256, 0, stream>>>(T, nullptr, Thi, Tlo);
  k_norm_split<<<N_SRC/4, 256, 0, stream>>>(S, gidx, Shi, Slo);

  for (int j_off = 0; j_off < N_TGT; j_off += cols) {
    dim3 gg(N_SRC / 128, cols / 128);
    k_gemm<<<gg, 256, 0, stream>>>(Shi, Slo, Thi, Tlo, simbuf, j_off);
    dim3 gp(NSLICE, cols);
    k_part1se<<<gp, 256, 0, stream>>>(simbuf, p1v, p1i, pse, j_off);
    k_assign<<<cols/64, 64, 0, stream>>>(p1v, p1i, sortedLab, assigned, j_off);
    k_part2n<<<cols, 256, 0, stream>>>(simbuf, assigned, startArr, p1v, pse,
                                       scores, contrastA, j_off);
  }
  k_finalize<<<1, 1024, 0, stream>>>(scores, contrastA, out);
}

// Round 8
// 1098.092 us; speedup vs baseline: 3.1673x; 1.1254x over previous
//
#include <hip/hip_runtime.h>
#include <cmath>
#include <cstdint>
#include <cstddef>
#include <climits>

#define N_SRC 65536
#define N_TGT 1024
#define DIM   256
#define TAU_INV (1.0f/0.07f)
#define LOSS_EPS 1e-6f
#define TOPSEL 512
#define N_CLASSES 345
#define SLICE_R 256
#define NS (N_SRC/SLICE_R)     // 256 row-slices

typedef __bf16 bf16x8 __attribute__((ext_vector_type(8)));
typedef float  f32x4  __attribute__((ext_vector_type(4)));

// ---------------- bf16 split helpers ------------------------------------------------
__device__ __forceinline__ unsigned short f2bf(float x) {
  unsigned u = __float_as_uint(x);
  unsigned r = (u + 0x7fffu + ((u >> 16) & 1u)) >> 16;
  return (unsigned short)r;
}
__device__ __forceinline__ float bf2f(unsigned short h) {
  return __uint_as_float(((unsigned)h) << 16);
}

// ---------------- top-5 insertion helpers -------------------------------------------
__device__ __forceinline__ void insert5_vi(float v[5], int id[5], float nv, int ni) {
  bool beats_last = (nv > v[4]) || (nv == v[4] && ni < id[4]);
  if (!beats_last) return;
  #pragma unroll
  for (int p = 4; p > 0; --p) {
    bool up = (nv > v[p-1]) || (nv == v[p-1] && ni < id[p-1]);
    if (up) { v[p] = v[p-1]; id[p] = id[p-1]; }
    else    { v[p] = nv; id[p] = ni; return; }
  }
  v[0] = nv; id[0] = ni;
}
__device__ __forceinline__ void insert5_v(float v[5], float nv) {
  if (!(nv > v[4])) return;
  #pragma unroll
  for (int p = 4; p > 0; --p) {
    if (nv > v[p-1]) v[p] = v[p-1];
    else { v[p] = nv; return; }
  }
  v[0] = nv;
}
__device__ __forceinline__ void wave_merge5_vi(float v[5], int id[5]) {
  #pragma unroll
  for (int off = 1; off < 64; off <<= 1) {
    float pv[5]; int pi[5];
    #pragma unroll
    for (int u = 0; u < 5; ++u) {
      pv[u] = __shfl_xor(v[u], off, 64);
      pi[u] = __shfl_xor(id[u], off, 64);
    }
    #pragma unroll
    for (int u = 0; u < 5; ++u) insert5_vi(v, id, pv[u], pi[u]);
  }
}
__device__ __forceinline__ void wave_merge5_v(float v[5]) {
  #pragma unroll
  for (int off = 1; off < 64; off <<= 1) {
    float pv[5];
    #pragma unroll
    for (int u = 0; u < 5; ++u) pv[u] = __shfl_xor(v[u], off, 64);
    #pragma unroll
    for (int u = 0; u < 5; ++u) insert5_v(v, pv[u]);
  }
}

// ---------------- preprocessing: counting sort of rows by label ---------------------
__global__ __launch_bounds__(512) void k_zero(int* __restrict__ hist) {
  if (threadIdx.x < N_CLASSES) hist[threadIdx.x] = 0;
}
__global__ __launch_bounds__(256) void k_hist(const int* __restrict__ labels,
                                              int* __restrict__ hist) {
  int i = blockIdx.x * 256 + threadIdx.x;
  atomicAdd(&hist[labels[i]], 1);
}
__global__ __launch_bounds__(64) void k_scan(const int* __restrict__ hist,
                                             int* __restrict__ start,
                                             int* __restrict__ cursor) {
  if (threadIdx.x == 0) {
    int acc = 0;
    for (int c = 0; c < N_CLASSES; ++c) {
      start[c] = acc; cursor[c] = acc; acc += hist[c];
    }
    start[N_CLASSES] = acc;
  }
}
__global__ __launch_bounds__(256) void k_perm(const int* __restrict__ labels,
                                              int* __restrict__ cursor,
                                              int* __restrict__ g,
                                              int* __restrict__ sortedLab) {
  int i = blockIdx.x * 256 + threadIdx.x;
  int l = labels[i];
  int slot = atomicAdd(&cursor[l], 1);
  g[slot] = i;
  sortedLab[slot] = l;
}

// ---------------- K1: row-normalize + split fp32 -> (hi, lo) bf16 -------------------
__global__ __launch_bounds__(256) void k_norm_split(const float* __restrict__ X,
                                                    const int* __restrict__ g,
                                                    unsigned short* __restrict__ hi,
                                                    unsigned short* __restrict__ lo) {
  int wave = threadIdx.x >> 6, lane = threadIdx.x & 63;
  int row  = blockIdx.x * 4 + wave;
  int src  = g ? g[row] : row;
  float4 v = reinterpret_cast<const float4*>(X + (size_t)src * DIM)[lane];
  float ss = v.x*v.x + v.y*v.y + v.z*v.z + v.w*v.w;
  #pragma unroll
  for (int o = 32; o > 0; o >>= 1) ss += __shfl_xor(ss, o, 64);
  float r = 1.0f / sqrtf(ss);
  v.x *= r; v.y *= r; v.z *= r; v.w *= r;
  ushort4 h, l;
  h.x = f2bf(v.x); l.x = f2bf(v.x - bf2f(h.x));
  h.y = f2bf(v.y); l.y = f2bf(v.y - bf2f(h.y));
  h.z = f2bf(v.z); l.z = f2bf(v.z - bf2f(h.z));
  h.w = f2bf(v.w); l.w = f2bf(v.w - bf2f(h.w));
  reinterpret_cast<ushort4*>(hi + (size_t)row * DIM)[lane] = h;
  reinterpret_cast<ushort4*>(lo + (size_t)row * DIM)[lane] = l;
}

// ---------------- K2: split-bf16 MFMA GEMM, TRANSPOSED output sim[i][j] -------------
// R0's measured-fastest structure; operand roles swapped so the MFMA register dim
// (row m = A-dim) is the TARGET index j: float4 store = 4 consecutive j at fixed i.
// A = targets (Thi/Tlo), B = sources (Shi/Slo). D map: row m=j (reg), col n=i (lane&15).
__device__ __forceinline__ void gl_lds(const unsigned short* g, unsigned short* d) {
  __builtin_amdgcn_global_load_lds(
      (const __attribute__((address_space(1))) unsigned int*)g,
      (__attribute__((address_space(3))) unsigned int*)d, 16, 0, 0);
}

__global__ __launch_bounds__(256) void k_gemm(
    const unsigned short* __restrict__ Ahi, const unsigned short* __restrict__ Alo,  // targets
    const unsigned short* __restrict__ Bhi, const unsigned short* __restrict__ Blo,  // sources
    float* __restrict__ simIJ, int cols, int j_off)
{
  __shared__ unsigned short As_hi[128*32];
  __shared__ unsigned short As_lo[128*32];
  __shared__ unsigned short Bs_hi[128*32];
  __shared__ unsigned short Bs_lo[128*32];

  const int tid  = threadIdx.x;
  const int lane = tid & 63;
  const int w    = tid >> 6;       // wave 0..3
  const int wm   = w & 1;          // target-dim half (M)
  const int wn   = w >> 1;         // source-dim half (N)
  const int i0   = blockIdx.x * 128;           // source block
  const int j0g  = j_off + blockIdx.y * 128;   // global target row (A loads)
  const int j0l  = blockIdx.y * 128;           // chunk-local target

  f32x4 acc[4][4];
  #pragma unroll
  for (int a = 0; a < 4; ++a)
    #pragma unroll
    for (int b = 0; b < 4; ++b) acc[a][b] = f32x4{0.f, 0.f, 0.f, 0.f};

  const int srow = (w << 5) + (lane >> 2);
  const int scol = (lane & 3) << 3;             // 8 bf16 = 16 B
  const unsigned short* gAh = Ahi + (size_t)(j0g + srow) * DIM + scol;
  const unsigned short* gAl = Alo + (size_t)(j0g + srow) * DIM + scol;
  const unsigned short* gBh = Bhi + (size_t)(i0  + srow) * DIM + scol;
  const unsigned short* gBl = Blo + (size_t)(i0  + srow) * DIM + scol;
  unsigned short* dA0  = &As_hi[(w << 5) * 32];
  unsigned short* dA1  = &As_hi[((w << 5) + 16) * 32];
  unsigned short* dB0  = &Bs_hi[(w << 5) * 32];
  unsigned short* dB1  = &Bs_hi[((w << 5) + 16) * 32];
  unsigned short* dA0l = &As_lo[(w << 5) * 32];
  unsigned short* dA1l = &As_lo[((w << 5) + 16) * 32];
  unsigned short* dB0l = &Bs_lo[(w << 5) * 32];
  unsigned short* dB1l = &Bs_lo[((w << 5) + 16) * 32];

  const int fr = lane & 15;
  const int fk = (lane >> 4) << 3;

  for (int k0 = 0; k0 < DIM; k0 += 32) {
    __syncthreads();
    gl_lds(gAh + k0,           dA0);
    gl_lds(gAh + k0 + 16*DIM,  dA1);
    gl_lds(gAl + k0,           dA0l);
    gl_lds(gAl + k0 + 16*DIM,  dA1l);
    gl_lds(gBh + k0,           dB0);
    gl_lds(gBh + k0 + 16*DIM,  dB1);
    gl_lds(gBl + k0,           dB0l);
    gl_lds(gBl + k0 + 16*DIM,  dB1l);
    __syncthreads();

    bf16x8 ah[4], al[4], bh[4], bl[4];
    #pragma unroll
    for (int rf = 0; rf < 4; ++rf) {
      int r = ((wm << 6) + (rf << 4) + fr) * 32 + fk;
      ah[rf] = *(const bf16x8*)&As_hi[r];
      al[rf] = *(const bf16x8*)&As_lo[r];
    }
    #pragma unroll
    for (int cf = 0; cf < 4; ++cf) {
      int r = ((wn << 6) + (cf << 4) + fr) * 32 + fk;
      bh[cf] = *(const bf16x8*)&Bs_hi[r];
      bl[cf] = *(const bf16x8*)&Bs_lo[r];
    }
    #pragma unroll
    for (int rf = 0; rf < 4; ++rf)
      #pragma unroll
      for (int cf = 0; cf < 4; ++cf) {
        acc[rf][cf] = __builtin_amdgcn_mfma_f32_16x16x32_bf16(ah[rf], bh[cf], acc[rf][cf], 0, 0, 0);
        acc[rf][cf] = __builtin_amdgcn_mfma_f32_16x16x32_bf16(ah[rf], bl[cf], acc[rf][cf], 0, 0, 0);
        acc[rf][cf] = __builtin_amdgcn_mfma_f32_16x16x32_bf16(al[rf], bh[cf], acc[rf][cf], 0, 0, 0);
      }
  }

  // store: m (reg dim) = target j-local, n (lane&15) = source i-local
  #pragma unroll
  for (int rf = 0; rf < 4; ++rf) {
    const int m_base = (wm << 6) + (rf << 4) + ((lane >> 4) << 2);
    #pragma unroll
    for (int cf = 0; cf < 4; ++cf) {
      const int n = (wn << 6) + (cf << 4) + (lane & 15);
      *reinterpret_cast<float4*>(&simIJ[(size_t)(i0 + n) * cols + j0l + m_base]) =
          make_float4(acc[rf][cf][0], acc[rf][cf][1], acc[rf][cf][2], acc[rf][cf][3]);
    }
  }
}

// ---------------- K3: per-slice per-column top-5 + sum-exp (lane-owns-column) -------
// Block = slice of 256 rows; 512 threads each own CPT columns, stream rows serially.
// No cross-lane merges, no LDS, no serial tail.
template<int CPT>
__global__ __launch_bounds__(512) void k_part1t(const float* __restrict__ sim,
                                                int cols,
                                                float* __restrict__ p1v,
                                                int* __restrict__ p1i,
                                                float* __restrict__ pse) {
  const int s  = blockIdx.x;
  const int t  = threadIdx.x;
  const int jc = t * CPT;
  if (jc >= cols) return;
  float tv0[5]; int ti0[5]; float se0 = 0.f;
  float tv1[5]; int ti1[5]; float se1 = 0.f;
  #pragma unroll
  for (int u = 0; u < 5; ++u) { tv0[u] = -INFINITY; ti0[u] = INT_MAX;
                                tv1[u] = -INFINITY; ti1[u] = INT_MAX; }
  const int i0 = s * SLICE_R;
  #pragma unroll 4
  for (int it = 0; it < SLICE_R; ++it) {
    const int i = i0 + it;
    if constexpr (CPT == 2) {
      float2 v = *reinterpret_cast<const float2*>(&sim[(size_t)i * cols + jc]);
      se0 += __expf(v.x * TAU_INV);
      se1 += __expf(v.y * TAU_INV);
      if (v.x > tv0[4]) insert5_vi(tv0, ti0, v.x, i);
      if (v.y > tv1[4]) insert5_vi(tv1, ti1, v.y, i);
    } else {
      float v = sim[(size_t)i * cols + jc];
      se0 += __expf(v * TAU_INV);
      if (v > tv0[4]) insert5_vi(tv0, ti0, v, i);
    }
  }
  {
    const size_t o = ((size_t)s * cols + jc) * 5;
    #pragma unroll
    for (int u = 0; u < 5; ++u) { p1v[o+u] = tv0[u]; p1i[o+u] = ti0[u]; }
    pse[(size_t)s * cols + jc] = se0;
  }
  if constexpr (CPT == 2) {
    const size_t o = ((size_t)s * cols + jc + 1) * 5;
    #pragma unroll
    for (int u = 0; u < 5; ++u) { p1v[o+u] = tv1[u]; p1i[o+u] = ti1[u]; }
    pse[(size_t)s * cols + jc + 1] = se1;
  }
}

// ---------------- K4: merge slice top-5s -> assigned label per column ---------------
__global__ __launch_bounds__(256) void k_assign(const float* __restrict__ p1v,
                                                const int* __restrict__ p1i,
                                                const int* __restrict__ sortedLab,
                                                int* __restrict__ assigned,
                                                int cols, int j_off) {
  const int w = threadIdx.x >> 6, lane = threadIdx.x & 63;
  const int jloc = blockIdx.x * 4 + w;
  float v[5]; int id[5];
  #pragma unroll
  for (int u = 0; u < 5; ++u) { v[u] = -INFINITY; id[u] = INT_MAX; }
  #pragma unroll
  for (int r = 0; r < NS/64; ++r) {
    const int s = r * 64 + lane;
    const size_t o = ((size_t)s * cols + jloc) * 5;
    #pragma unroll
    for (int u = 0; u < 5; ++u) insert5_vi(v, id, p1v[o+u], p1i[o+u]);
  }
  wave_merge5_vi(v, id);
  if (lane == 0) {
    int lab[5];
    #pragma unroll
    for (int a = 0; a < 5; ++a) lab[a] = sortedLab[id[a]];
    int bestSc = INT_MIN, bestA = 0;
    #pragma unroll
    for (int a = 0; a < 5; ++a) {
      int c = 0;
      #pragma unroll
      for (int b = 0; b < 5; ++b) c += (lab[b] == lab[a]) ? 1 : 0;
      int sc = c * 1000000 - lab[a];
      if (sc > bestSc) { bestSc = sc; bestA = a; }
    }
    assigned[j_off + jloc] = lab[bestA];
  }
}

// ---------------- K5: targeted pass2 (wave per column) ------------------------------
// Matched rows = [start[asg], start[asg+1]) span <=2-3 slices of 256 (label-sorted).
// Stream covering slices (strided 4B gathers, classify matched/unmatched); fold the
// stored top-5s of all other slices into ut (provably unmatched); se = sum pse.
__global__ __launch_bounds__(256) void k_part2n(const float* __restrict__ sim,
                                                const int* __restrict__ assigned,
                                                const int* __restrict__ start,
                                                const float* __restrict__ p1v,
                                                const float* __restrict__ pse,
                                                float* __restrict__ scores,
                                                float* __restrict__ contrast,
                                                int cols, int j_off) {
  const int w = threadIdx.x >> 6, lane = threadIdx.x & 63;
  const int jloc = blockIdx.x * 4 + w;
  const int j    = j_off + jloc;
  const int asg  = assigned[j];
  const int a    = start[asg];
  const int b    = start[asg + 1];
  const int s0   = a >> 8;
  const int s1   = (b - 1) >> 8;

  float mt[5], ut[5]; float sem = 0.f, se = 0.f;
  #pragma unroll
  for (int u = 0; u < 5; ++u) { mt[u] = -INFINITY; ut[u] = -INFINITY; }

  for (int i = s0 * SLICE_R + lane; i < (s1 + 1) * SLICE_R; i += 64) {
    float v = sim[(size_t)i * cols + jloc];
    if (i >= a && i < b) { sem += __expf(v * TAU_INV); insert5_v(mt, v); }
    else insert5_v(ut, v);
  }
  #pragma unroll
  for (int r = 0; r < NS/64; ++r) {
    const int s = r * 64 + lane;
    se += pse[(size_t)s * cols + jloc];
    if (s < s0 || s > s1) {
      const size_t o = ((size_t)s * cols + jloc) * 5;
      #pragma unroll
      for (int u = 0; u < 5; ++u) insert5_v(ut, p1v[o+u]);
    }
  }
  #pragma unroll
  for (int o = 32; o > 0; o >>= 1) { sem += __shfl_xor(sem, o, 64); se += __shfl_xor(se, o, 64); }
  wave_merge5_v(mt);
  wave_merge5_v(ut);
  if (lane == 0) {
    float nln = 0.f, nun = 0.f;
    #pragma unroll
    for (int u = 0; u < 5; ++u) {
      if (mt[u] > -1e30f) nln += mt[u];
      if (ut[u] > -1e30f) nun += ut[u];
    }
    scores[j]   = nln / nun;
    contrast[j] = sem / se;
  }
}

// ---------------- K6: top-512 selection + loss --------------------------------------
__global__ __launch_bounds__(1024) void k_finalize(const float* __restrict__ scores,
                                                   const float* __restrict__ contrast,
                                                   float* __restrict__ out) {
  __shared__ float sc[N_TGT];
  __shared__ float red[N_TGT];
  const int j = threadIdx.x;
  sc[j] = scores[j];
  __syncthreads();
  float my = sc[j];
  int rank = 0;
  for (int m = 0; m < N_TGT; ++m) {
    float s = sc[m];
    rank += ((s > my) || (s == my && m < j)) ? 1 : 0;
  }
  red[j] = (rank < TOPSEL) ? logf(contrast[j] + LOSS_EPS) : 0.0f;
  __syncthreads();
  for (int s = 512; s > 0; s >>= 1) { if (j < s) red[j] += red[j+s]; __syncthreads(); }
  if (j == 0) out[0] = -red[0] / (float)TOPSEL;
}

// ---------------- launcher ----------------------------------------------------------
extern "C" void kernel_launch(void* const* d_in, const int* in_sizes, int n_in,
                              void* d_out, int out_size, void* d_ws, size_t ws_size,
                              hipStream_t stream) {
  const float* S      = (const float*)d_in[0];
  const int*   labels = (const int*)d_in[1];
  const float* T      = (const float*)d_in[2];
  float* out = (float*)d_out;

  float* ws = (float*)d_ws;
  float* scores    = ws;                                    // 1024
  float* contrastA = scores + N_TGT;                        // 1024
  int*   assigned  = (int*)(contrastA + N_TGT);             // 1024
  float* p1v       = (float*)(assigned + N_TGT);            // NS*1024*5 = 1.31M f
  int*   p1i       = (int*)(p1v + (size_t)NS*N_TGT*5);      // 1.31M i
  float* pse       = (float*)(p1i + (size_t)NS*N_TGT*5);    // NS*1024 = 0.26M f
  int*   hist      = (int*)(pse + (size_t)NS*N_TGT);        // 345
  int*   startArr  = hist + N_CLASSES;                      // 346
  int*   cursor    = startArr + (N_CLASSES + 1);            // 345
  int*   gidx      = cursor + N_CLASSES;                    // 65536
  int*   sortedLab = gidx + N_SRC;                          // 65536
  unsigned short* Shi = (unsigned short*)(sortedLab + N_SRC);
  unsigned short* Slo = Shi + (size_t)N_SRC*DIM;
  unsigned short* Thi = Slo + (size_t)N_SRC*DIM;
  unsigned short* Tlo = Thi + (size_t)N_TGT*DIM;
  float* simbuf       = (float*)(Tlo + (size_t)N_TGT*DIM);

  size_t head  = (size_t)(simbuf - ws);
  size_t avail = (ws_size / 4 > head) ? (ws_size / 4 - head) : 0;
  int cols = 128;
  if      (avail >= (size_t)1024 * N_SRC) cols = 1024;
  else if (avail >= (size_t)512  * N_SRC) cols = 512;
  else if (avail >= (size_t)256  * N_SRC) cols = 256;

  // preprocessing: counting sort of source rows by label
  k_zero<<<1, 512, 0, stream>>>(hist);
  k_hist<<<N_SRC/256, 256, 0, stream>>>(labels, hist);
  k_scan<<<1, 64, 0, stream>>>(hist, startArr, cursor);
  k_perm<<<N_SRC/256, 256, 0, stream>>>(labels, cursor, gidx, sortedLab);

  k_norm_split<<<N_TGT/4, 256, 0, stream>>>(T, nullptr, Thi, Tlo);
  k_norm_split<<<N_SRC/4, 256, 0, stream>>>(S, gidx, Shi, Slo);

  for (int j_off = 0; j_off < N_TGT; j_off += cols) {
    dim3 gg(N_SRC / 128, cols / 128);
    k_gemm<<<gg, 256, 0, stream>>>(Thi, Tlo, Shi, Slo, simbuf, cols, j_off);
    if (cols >= 1024)
      k_part1t<2><<<NS, 512, 0, stream>>>(simbuf, cols, p1v, p1i, pse);
    else
      k_part1t<1><<<NS, 512, 0, stream>>>(simbuf, cols, p1v, p1i, pse);
    k_assign<<<cols/4, 256, 0, stream>>>(p1v, p1i, sortedLab, assigned, cols, j_off);
    k_part2n<<<cols/4, 256, 0, stream>>>(simbuf, assigned, startArr, p1v, pse,
                                         scores, contrastA, cols, j_off);
  }
  k_finalize<<<1, 1024, 0, stream>>>(scores, contrastA, out);
}

// Round 9
// 1033.831 us; speedup vs baseline: 3.3642x; 1.0622x over previous
//
#include <hip/hip_runtime.h>
#include <cmath>
#include <cstdint>
#include <cstddef>
#include <climits>

#define N_SRC 65536
#define N_TGT 1024
#define DIM   256
#define TAU_INV (1.0f/0.07f)
#define LOSS_EPS 1e-6f
#define TOPSEL 512
#define N_CLASSES 345
#define SLICE_R 64
#define NS (N_SRC/SLICE_R)     // 1024 row-slices

typedef __bf16 bf16x8 __attribute__((ext_vector_type(8)));
typedef float  f32x4  __attribute__((ext_vector_type(4)));

// ---------------- bf16 split helpers ------------------------------------------------
__device__ __forceinline__ unsigned short f2bf(float x) {
  unsigned u = __float_as_uint(x);
  unsigned r = (u + 0x7fffu + ((u >> 16) & 1u)) >> 16;
  return (unsigned short)r;
}
__device__ __forceinline__ float bf2f(unsigned short h) {
  return __uint_as_float(((unsigned)h) << 16);
}

// ---------------- top-5 insertion helpers -------------------------------------------
__device__ __forceinline__ void insert5_vi(float v[5], int id[5], float nv, int ni) {
  bool beats_last = (nv > v[4]) || (nv == v[4] && ni < id[4]);
  if (!beats_last) return;
  #pragma unroll
  for (int p = 4; p > 0; --p) {
    bool up = (nv > v[p-1]) || (nv == v[p-1] && ni < id[p-1]);
    if (up) { v[p] = v[p-1]; id[p] = id[p-1]; }
    else    { v[p] = nv; id[p] = ni; return; }
  }
  v[0] = nv; id[0] = ni;
}
__device__ __forceinline__ void insert5_v(float v[5], float nv) {
  if (!(nv > v[4])) return;
  #pragma unroll
  for (int p = 4; p > 0; --p) {
    if (nv > v[p-1]) v[p] = v[p-1];
    else { v[p] = nv; return; }
  }
  v[0] = nv;
}
__device__ __forceinline__ void wave_merge5_vi(float v[5], int id[5]) {
  #pragma unroll
  for (int off = 1; off < 64; off <<= 1) {
    float pv[5]; int pi[5];
    #pragma unroll
    for (int u = 0; u < 5; ++u) {
      pv[u] = __shfl_xor(v[u], off, 64);
      pi[u] = __shfl_xor(id[u], off, 64);
    }
    #pragma unroll
    for (int u = 0; u < 5; ++u) insert5_vi(v, id, pv[u], pi[u]);
  }
}
__device__ __forceinline__ void wave_merge5_v(float v[5]) {
  #pragma unroll
  for (int off = 1; off < 64; off <<= 1) {
    float pv[5];
    #pragma unroll
    for (int u = 0; u < 5; ++u) pv[u] = __shfl_xor(v[u], off, 64);
    #pragma unroll
    for (int u = 0; u < 5; ++u) insert5_v(v, pv[u]);
  }
}

// ---------------- preprocessing: counting sort of rows by label ---------------------
__global__ __launch_bounds__(512) void k_zero(int* __restrict__ hist) {
  if (threadIdx.x < N_CLASSES) hist[threadIdx.x] = 0;
}
__global__ __launch_bounds__(256) void k_hist(const int* __restrict__ labels,
                                              int* __restrict__ hist) {
  int i = blockIdx.x * 256 + threadIdx.x;
  atomicAdd(&hist[labels[i]], 1);
}
__global__ __launch_bounds__(64) void k_scan(const int* __restrict__ hist,
                                             int* __restrict__ start,
                                             int* __restrict__ cursor) {
  if (threadIdx.x == 0) {
    int acc = 0;
    for (int c = 0; c < N_CLASSES; ++c) {
      start[c] = acc; cursor[c] = acc; acc += hist[c];
    }
    start[N_CLASSES] = acc;
  }
}
__global__ __launch_bounds__(256) void k_perm(const int* __restrict__ labels,
                                              int* __restrict__ cursor,
                                              int* __restrict__ g,
                                              int* __restrict__ sortedLab) {
  int i = blockIdx.x * 256 + threadIdx.x;
  int l = labels[i];
  int slot = atomicAdd(&cursor[l], 1);
  g[slot] = i;
  sortedLab[slot] = l;
}

// ---------------- K1: row-normalize + split fp32 -> (hi, lo) bf16 -------------------
__global__ __launch_bounds__(256) void k_norm_split(const float* __restrict__ X,
                                                    const int* __restrict__ g,
                                                    unsigned short* __restrict__ hi,
                                                    unsigned short* __restrict__ lo) {
  int wave = threadIdx.x >> 6, lane = threadIdx.x & 63;
  int row  = blockIdx.x * 4 + wave;
  int src  = g ? g[row] : row;
  float4 v = reinterpret_cast<const float4*>(X + (size_t)src * DIM)[lane];
  float ss = v.x*v.x + v.y*v.y + v.z*v.z + v.w*v.w;
  #pragma unroll
  for (int o = 32; o > 0; o >>= 1) ss += __shfl_xor(ss, o, 64);
  float r = 1.0f / sqrtf(ss);
  v.x *= r; v.y *= r; v.z *= r; v.w *= r;
  ushort4 h, l;
  h.x = f2bf(v.x); l.x = f2bf(v.x - bf2f(h.x));
  h.y = f2bf(v.y); l.y = f2bf(v.y - bf2f(h.y));
  h.z = f2bf(v.z); l.z = f2bf(v.z - bf2f(h.z));
  h.w = f2bf(v.w); l.w = f2bf(v.w - bf2f(h.w));
  reinterpret_cast<ushort4*>(hi + (size_t)row * DIM)[lane] = h;
  reinterpret_cast<ushort4*>(lo + (size_t)row * DIM)[lane] = l;
}

// ---------------- K2: split-bf16 MFMA GEMM, transposed output sim[i][j] -------------
// R0's measured-fastest structure. A = targets, B = sources; float4 store covers
// 4 consecutive j at fixed i. 1-D grid with bijective XCD swizzle: the nby blocks
// sharing one A panel run consecutively on one XCD -> A fetched once per chunk.
__device__ __forceinline__ void gl_lds(const unsigned short* g, unsigned short* d) {
  __builtin_amdgcn_global_load_lds(
      (const __attribute__((address_space(1))) unsigned int*)g,
      (__attribute__((address_space(3))) unsigned int*)d, 16, 0, 0);
}

__global__ __launch_bounds__(256) void k_gemm(
    const unsigned short* __restrict__ Ahi, const unsigned short* __restrict__ Alo,  // targets
    const unsigned short* __restrict__ Bhi, const unsigned short* __restrict__ Blo,  // sources
    float* __restrict__ simIJ, int cols, int j_off)
{
  __shared__ unsigned short As_hi[128*32];
  __shared__ unsigned short As_lo[128*32];
  __shared__ unsigned short Bs_hi[128*32];
  __shared__ unsigned short Bs_lo[128*32];

  const int tid  = threadIdx.x;
  const int lane = tid & 63;
  const int w    = tid >> 6;       // wave 0..3
  const int wm   = w & 1;          // target-dim half (M)
  const int wn   = w >> 1;         // source-dim half (N)

  // XCD-locality swizzle: c = XCD, k/nby = source block, k%nby = target block
  const int nby = cols >> 7;
  const int d   = blockIdx.x;                  // grid = 512 * nby (multiple of 8)
  const int c   = d & 7;
  const int kk  = d >> 3;
  const int by  = kk % nby;
  const int bx  = (kk / nby) * 8 + c;
  const int i0   = bx * 128;                   // source block
  const int j0g  = j_off + by * 128;           // global target row (A loads)
  const int j0l  = by * 128;                   // chunk-local target

  f32x4 acc[4][4];
  #pragma unroll
  for (int a = 0; a < 4; ++a)
    #pragma unroll
    for (int b = 0; b < 4; ++b) acc[a][b] = f32x4{0.f, 0.f, 0.f, 0.f};

  const int srow = (w << 5) + (lane >> 2);
  const int scol = (lane & 3) << 3;             // 8 bf16 = 16 B
  const unsigned short* gAh = Ahi + (size_t)(j0g + srow) * DIM + scol;
  const unsigned short* gAl = Alo + (size_t)(j0g + srow) * DIM + scol;
  const unsigned short* gBh = Bhi + (size_t)(i0  + srow) * DIM + scol;
  const unsigned short* gBl = Blo + (size_t)(i0  + srow) * DIM + scol;
  unsigned short* dA0  = &As_hi[(w << 5) * 32];
  unsigned short* dA1  = &As_hi[((w << 5) + 16) * 32];
  unsigned short* dB0  = &Bs_hi[(w << 5) * 32];
  unsigned short* dB1  = &Bs_hi[((w << 5) + 16) * 32];
  unsigned short* dA0l = &As_lo[(w << 5) * 32];
  unsigned short* dA1l = &As_lo[((w << 5) + 16) * 32];
  unsigned short* dB0l = &Bs_lo[(w << 5) * 32];
  unsigned short* dB1l = &Bs_lo[((w << 5) + 16) * 32];

  const int fr = lane & 15;
  const int fk = (lane >> 4) << 3;

  for (int k0 = 0; k0 < DIM; k0 += 32) {
    __syncthreads();
    gl_lds(gAh + k0,           dA0);
    gl_lds(gAh + k0 + 16*DIM,  dA1);
    gl_lds(gAl + k0,           dA0l);
    gl_lds(gAl + k0 + 16*DIM,  dA1l);
    gl_lds(gBh + k0,           dB0);
    gl_lds(gBh + k0 + 16*DIM,  dB1);
    gl_lds(gBl + k0,           dB0l);
    gl_lds(gBl + k0 + 16*DIM,  dB1l);
    __syncthreads();

    bf16x8 ah[4], al[4], bh[4], bl[4];
    #pragma unroll
    for (int rf = 0; rf < 4; ++rf) {
      int r = ((wm << 6) + (rf << 4) + fr) * 32 + fk;
      ah[rf] = *(const bf16x8*)&As_hi[r];
      al[rf] = *(const bf16x8*)&As_lo[r];
    }
    #pragma unroll
    for (int cf = 0; cf < 4; ++cf) {
      int r = ((wn << 6) + (cf << 4) + fr) * 32 + fk;
      bh[cf] = *(const bf16x8*)&Bs_hi[r];
      bl[cf] = *(const bf16x8*)&Bs_lo[r];
    }
    #pragma unroll
    for (int rf = 0; rf < 4; ++rf)
      #pragma unroll
      for (int cf = 0; cf < 4; ++cf) {
        acc[rf][cf] = __builtin_amdgcn_mfma_f32_16x16x32_bf16(ah[rf], bh[cf], acc[rf][cf], 0, 0, 0);
        acc[rf][cf] = __builtin_amdgcn_mfma_f32_16x16x32_bf16(ah[rf], bl[cf], acc[rf][cf], 0, 0, 0);
        acc[rf][cf] = __builtin_amdgcn_mfma_f32_16x16x32_bf16(al[rf], bh[cf], acc[rf][cf], 0, 0, 0);
      }
  }

  // store: m (reg dim) = target j-local, n (lane&15) = source i-local
  #pragma unroll
  for (int rf = 0; rf < 4; ++rf) {
    const int m_base = (wm << 6) + (rf << 4) + ((lane >> 4) << 2);
    #pragma unroll
    for (int cf = 0; cf < 4; ++cf) {
      const int n = (wn << 6) + (cf << 4) + (lane & 15);
      *reinterpret_cast<float4*>(&simIJ[(size_t)(i0 + n) * cols + j0l + m_base]) =
          make_float4(acc[rf][cf][0], acc[rf][cf][1], acc[rf][cf][2], acc[rf][cf][3]);
    }
  }
}

// ---------------- K3: per-slice per-column top-5 + sum-exp (lane-owns-column) -------
// Block = slice of 64 rows; `cols` threads each own 1 column, stream rows serially.
// NS=1024 blocks -> 4 blocks/CU -> full wave occupancy for latency hiding.
__global__ __launch_bounds__(1024) void k_part1t(const float* __restrict__ sim,
                                                 int cols,
                                                 float* __restrict__ p1v,
                                                 int* __restrict__ p1i,
                                                 float* __restrict__ pse) {
  const int s  = blockIdx.x;
  const int jc = threadIdx.x;
  float tv0[5]; int ti0[5]; float se0 = 0.f;
  #pragma unroll
  for (int u = 0; u < 5; ++u) { tv0[u] = -INFINITY; ti0[u] = INT_MAX; }
  const int i0 = s * SLICE_R;
  const float* p = sim + (size_t)i0 * cols + jc;
  #pragma unroll 8
  for (int it = 0; it < SLICE_R; ++it) {
    float v = p[(size_t)it * cols];
    se0 += __expf(v * TAU_INV);
    if (v > tv0[4]) insert5_vi(tv0, ti0, v, i0 + it);
  }
  const size_t o = ((size_t)s * cols + jc) * 5;
  #pragma unroll
  for (int u = 0; u < 5; ++u) { p1v[o+u] = tv0[u]; p1i[o+u] = ti0[u]; }
  pse[(size_t)s * cols + jc] = se0;
}

// ---------------- K4: merge slice top-5s -> assigned label per column ---------------
__global__ __launch_bounds__(256) void k_assign(const float* __restrict__ p1v,
                                                const int* __restrict__ p1i,
                                                const int* __restrict__ sortedLab,
                                                int* __restrict__ assigned,
                                                int cols, int j_off) {
  const int w = threadIdx.x >> 6, lane = threadIdx.x & 63;
  const int jloc = blockIdx.x * 4 + w;
  float v[5]; int id[5];
  #pragma unroll
  for (int u = 0; u < 5; ++u) { v[u] = -INFINITY; id[u] = INT_MAX; }
  #pragma unroll
  for (int r = 0; r < NS/64; ++r) {
    const int s = r * 64 + lane;
    const size_t o = ((size_t)s * cols + jloc) * 5;
    #pragma unroll
    for (int u = 0; u < 5; ++u) insert5_vi(v, id, p1v[o+u], p1i[o+u]);
  }
  wave_merge5_vi(v, id);
  if (lane == 0) {
    int lab[5];
    #pragma unroll
    for (int a = 0; a < 5; ++a) lab[a] = sortedLab[id[a]];
    int bestSc = INT_MIN, bestA = 0;
    #pragma unroll
    for (int a = 0; a < 5; ++a) {
      int c = 0;
      #pragma unroll
      for (int b = 0; b < 5; ++b) c += (lab[b] == lab[a]) ? 1 : 0;
      int sc = c * 1000000 - lab[a];
      if (sc > bestSc) { bestSc = sc; bestA = a; }
    }
    assigned[j_off + jloc] = lab[bestA];
  }
}

// ---------------- K5: targeted pass2 (wave per column) ------------------------------
// Matched rows = [start[asg], start[asg+1]) span a few 64-row slices (label-sorted).
// Stream covering slices; fold stored top-5s of all other slices into ut (provably
// unmatched); se = sum pse. Score+contrast inline.
__global__ __launch_bounds__(256) void k_part2n(const float* __restrict__ sim,
                                                const int* __restrict__ assigned,
                                                const int* __restrict__ start,
                                                const float* __restrict__ p1v,
                                                const float* __restrict__ pse,
                                                float* __restrict__ scores,
                                                float* __restrict__ contrast,
                                                int cols, int j_off) {
  const int w = threadIdx.x >> 6, lane = threadIdx.x & 63;
  const int jloc = blockIdx.x * 4 + w;
  const int j    = j_off + jloc;
  const int asg  = assigned[j];
  const int a    = start[asg];
  const int b    = start[asg + 1];
  const int s0   = a >> 6;
  const int s1   = (b - 1) >> 6;

  float mt[5], ut[5]; float sem = 0.f, se = 0.f;
  #pragma unroll
  for (int u = 0; u < 5; ++u) { mt[u] = -INFINITY; ut[u] = -INFINITY; }

  for (int i = s0 * SLICE_R + lane; i < (s1 + 1) * SLICE_R; i += 64) {
    float v = sim[(size_t)i * cols + jloc];
    if (i >= a && i < b) { sem += __expf(v * TAU_INV); insert5_v(mt, v); }
    else insert5_v(ut, v);
  }
  #pragma unroll
  for (int r = 0; r < NS/64; ++r) {
    const int s = r * 64 + lane;
    se += pse[(size_t)s * cols + jloc];
    if (s < s0 || s > s1) {
      const size_t o = ((size_t)s * cols + jloc) * 5;
      #pragma unroll
      for (int u = 0; u < 5; ++u) insert5_v(ut, p1v[o+u]);
    }
  }
  #pragma unroll
  for (int o = 32; o > 0; o >>= 1) { sem += __shfl_xor(sem, o, 64); se += __shfl_xor(se, o, 64); }
  wave_merge5_v(mt);
  wave_merge5_v(ut);
  if (lane == 0) {
    float nln = 0.f, nun = 0.f;
    #pragma unroll
    for (int u = 0; u < 5; ++u) {
      if (mt[u] > -1e30f) nln += mt[u];
      if (ut[u] > -1e30f) nun += ut[u];
    }
    scores[j]   = nln / nun;
    contrast[j] = sem / se;
  }
}

// ---------------- K6: top-512 selection + loss --------------------------------------
__global__ __launch_bounds__(1024) void k_finalize(const float* __restrict__ scores,
                                                   const float* __restrict__ contrast,
                                                   float* __restrict__ out) {
  __shared__ float sc[N_TGT];
  __shared__ float red[N_TGT];
  const int j = threadIdx.x;
  sc[j] = scores[j];
  __syncthreads();
  float my = sc[j];
  int rank = 0;
  for (int m = 0; m < N_TGT; ++m) {
    float s = sc[m];
    rank += ((s > my) || (s == my && m < j)) ? 1 : 0;
  }
  red[j] = (rank < TOPSEL) ? logf(contrast[j] + LOSS_EPS) : 0.0f;
  __syncthreads();
  for (int s = 512; s > 0; s >>= 1) { if (j < s) red[j] += red[j+s]; __syncthreads(); }
  if (j == 0) out[0] = -red[0] / (float)TOPSEL;
}

// ---------------- launcher ----------------------------------------------------------
extern "C" void kernel_launch(void* const* d_in, const int* in_sizes, int n_in,
                              void* d_out, int out_size, void* d_ws, size_t ws_size,
                              hipStream_t stream) {
  const float* S      = (const float*)d_in[0];
  const int*   labels = (const int*)d_in[1];
  const float* T      = (const float*)d_in[2];
  float* out = (float*)d_out;

  float* ws = (float*)d_ws;
  float* scores    = ws;                                    // 1024
  float* contrastA = scores + N_TGT;                        // 1024
  int*   assigned  = (int*)(contrastA + N_TGT);             // 1024
  float* p1v       = (float*)(assigned + N_TGT);            // NS*1024*5 = 5.24M f
  int*   p1i       = (int*)(p1v + (size_t)NS*N_TGT*5);      // 5.24M i
  float* pse       = (float*)(p1i + (size_t)NS*N_TGT*5);    // NS*1024 = 1.05M f
  int*   hist      = (int*)(pse + (size_t)NS*N_TGT);        // 345
  int*   startArr  = hist + N_CLASSES;                      // 346
  int*   cursor    = startArr + (N_CLASSES + 1);            // 345
  int*   gidx      = cursor + N_CLASSES;                    // 65536
  int*   sortedLab = gidx + N_SRC;                          // 65536
  unsigned short* Shi = (unsigned short*)(sortedLab + N_SRC);
  unsigned short* Slo = Shi + (size_t)N_SRC*DIM;
  unsigned short* Thi = Slo + (size_t)N_SRC*DIM;
  unsigned short* Tlo = Thi + (size_t)N_TGT*DIM;
  float* simbuf       = (float*)(Tlo + (size_t)N_TGT*DIM);

  size_t head  = (size_t)(simbuf - ws);
  size_t avail = (ws_size / 4 > head) ? (ws_size / 4 - head) : 0;
  int cols = 128;
  if      (avail >= (size_t)1024 * N_SRC) cols = 1024;
  else if (avail >= (size_t)512  * N_SRC) cols = 512;
  else if (avail >= (size_t)256  * N_SRC) cols = 256;

  // preprocessing: counting sort of source rows by label
  k_zero<<<1, 512, 0, stream>>>(hist);
  k_hist<<<N_SRC/256, 256, 0, stream>>>(labels, hist);
  k_scan<<<1, 64, 0, stream>>>(hist, startArr, cursor);
  k_perm<<<N_SRC/256, 256, 0, stream>>>(labels, cursor, gidx, sortedLab);

  k_norm_split<<<N_TGT/4, 256, 0, stream>>>(T, nullptr, Thi, Tlo);
  k_norm_split<<<N_SRC/4, 256, 0, stream>>>(S, gidx, Shi, Slo);

  for (int j_off = 0; j_off < N_TGT; j_off += cols) {
    k_gemm<<<(N_SRC/128) * (cols/128), 256, 0, stream>>>(Thi, Tlo, Shi, Slo,
                                                         simbuf, cols, j_off);
    k_part1t<<<NS, cols, 0, stream>>>(simbuf, cols, p1v, p1i, pse);
    k_assign<<<cols/4, 256, 0, stream>>>(p1v, p1i, sortedLab, assigned, cols, j_off);
    k_part2n<<<cols/4, 256, 0, stream>>>(simbuf, assigned, startArr, p1v, pse,
                                         scores, contrastA, cols, j_off);
  }
  k_finalize<<<1, 1024, 0, stream>>>(scores, contrastA, out);
}